// Round 4
// baseline (1466.405 us; speedup 1.0000x reference)
//
#include <hip/hip_runtime.h>

static constexpr int NLr = 2048;    // ligand rows
static constexpr int NPr = 16384;   // protein rows
static constexpr int DIM = 256;     // feature dim
static constexpr int NB  = 32;      // batch count

typedef unsigned short bf16_t;

__device__ inline float bf2f(bf16_t u){
  union { unsigned int i; float f; } c; c.i = ((unsigned int)u) << 16; return c.f;
}
__device__ inline bf16_t f2bf(float f){
  union { float f; unsigned int i; } c; c.f = f;
  unsigned int x = c.i;
  return (bf16_t)((x + 0x7fffu + ((x >> 16) & 1u)) >> 16);  // RNE
}

// fmt: 0 = bf16, 1 = fp32.  idx must be a multiple of 4 for ld4.
__device__ inline void ld4(const void* p, size_t idx, int fmt, float* o){
  if (fmt){
    float4 f = *reinterpret_cast<const float4*>((const float*)p + idx);
    o[0]=f.x; o[1]=f.y; o[2]=f.z; o[3]=f.w;
  } else {
    ushort4 u = *reinterpret_cast<const ushort4*>((const bf16_t*)p + idx);
    o[0]=bf2f(u.x); o[1]=bf2f(u.y); o[2]=bf2f(u.z); o[3]=bf2f(u.w);
  }
}
__device__ inline float ld1(const void* p, size_t idx, int fmt){
  return fmt ? ((const float*)p)[idx] : bf2f(((const bf16_t*)p)[idx]);
}

__device__ inline float wave_sum(float x){
  #pragma unroll
  for (int off = 32; off; off >>= 1) x += __shfl_xor(x, off, 64);
  return x;
}

// ---- dtype detector: bf16 data has no exponent-0xFF ushorts; fp32 data read as
// ushorts has ~0.78% of them (low mantissa halves are ~uniform bits). ----
__global__ void detect_kernel(const void* __restrict__ buf, int nelem, int* __restrict__ flag){
  __shared__ int cnt;
  if (threadIdx.x == 0) cnt = 0;
  __syncthreads();
  const unsigned short* u = (const unsigned short*)buf;
  int c = 0;
  for (int i = threadIdx.x; i < nelem; i += blockDim.x){
    unsigned short e = (u[i] >> 7) & 0xFFu;
    if (e == 0xFFu) c++;
  }
  atomicAdd(&cnt, c);
  __syncthreads();
  if (threadIdx.x == 0) *flag = (cnt > 8) ? 1 : 0;   // 1 = fp32, 0 = bf16
}

// ---- batch block boundaries via binary search (batch ids are sorted) ----
__global__ void bounds_kernel(const int* __restrict__ lb, const int* __restrict__ pb,
                              int* __restrict__ ls, int* __restrict__ ps){
  int t = threadIdx.x;
  if (t <= NB){
    int lo = 0, hi = NLr;
    while (lo < hi){ int mid = (lo + hi) >> 1; if (lb[mid] < t) lo = mid + 1; else hi = mid; }
    ls[t] = lo;
    lo = 0; hi = NPr;
    while (lo < hi){ int mid = (lo + hi) >> 1; if (pb[mid] < t) lo = mid + 1; else hi = mid; }
    ps[t] = lo;
  }
}

// ---- C[i,n] = sum_k A[k,i]*B[k,n]  (A^T B), 256x256, inputs mode-typed, C bf16 ----
__global__ __launch_bounds__(256) void wprod_atb(const int* __restrict__ mode_p,
    const void* __restrict__ A, const void* __restrict__ B, bf16_t* __restrict__ C){
  int mode = *mode_p;
  __shared__ float As[16][68];
  __shared__ float Bs[16][68];
  const int t  = threadIdx.x;
  const int kk = t >> 4;           // 0..15
  const int c0 = (t & 15) << 2;    // 0..60
  const int tx = t & 15, ty = t >> 4;
  const int bm = blockIdx.x, bn = blockIdx.y;
  float acc[4][4] = {};
  for (int kt = 0; kt < DIM; kt += 16){
    float av[4], bv[4];
    ld4(A, (size_t)(kt+kk)*DIM + bm*64 + c0, mode, av);
    ld4(B, (size_t)(kt+kk)*DIM + bn*64 + c0, mode, bv);
    #pragma unroll
    for (int q = 0; q < 4; q++){ As[kk][c0+q]=av[q]; Bs[kk][c0+q]=bv[q]; }
    __syncthreads();
    #pragma unroll
    for (int k = 0; k < 16; k++){
      float a[4], b[4];
      #pragma unroll
      for (int i = 0; i < 4; i++) a[i] = As[k][ty*4+i];
      #pragma unroll
      for (int j = 0; j < 4; j++) b[j] = Bs[k][tx*4+j];
      #pragma unroll
      for (int i = 0; i < 4; i++)
        #pragma unroll
        for (int j = 0; j < 4; j++)
          acc[i][j] += a[i]*b[j];
    }
    __syncthreads();
  }
  #pragma unroll
  for (int i = 0; i < 4; i++){
    ushort4 o;
    o.x=f2bf(acc[i][0]); o.y=f2bf(acc[i][1]); o.z=f2bf(acc[i][2]); o.w=f2bf(acc[i][3]);
    *reinterpret_cast<ushort4*>(C + (size_t)(bm*64+ty*4+i)*DIM + bn*64 + tx*4) = o;
  }
}

// ---- C[i,n] = sum_m A[m,i]*B[n,m]  (A^T B^T), 256x256, inputs mode-typed, C bf16 ----
__global__ __launch_bounds__(256) void wprod_atbt(const int* __restrict__ mode_p,
    const void* __restrict__ A, const void* __restrict__ B, bf16_t* __restrict__ C){
  int mode = *mode_p;
  __shared__ float As[16][68];
  __shared__ float Bs[64][17];
  const int t  = threadIdx.x;
  const int kk = t >> 4;           // 0..15 (m-chunk for A)
  const int c0 = (t & 15) << 2;    // 0..60 (i for A)
  const int r  = t >> 2;           // 0..63 (n for B)
  const int k0 = (t & 3) << 2;     // 0..12 (m for B)
  const int tx = t & 15, ty = t >> 4;
  const int bm = blockIdx.x, bn = blockIdx.y;
  float acc[4][4] = {};
  for (int mt = 0; mt < DIM; mt += 16){
    float av[4], bv[4];
    ld4(A, (size_t)(mt+kk)*DIM + bm*64 + c0, mode, av);
    ld4(B, (size_t)(bn*64+r)*DIM + mt + k0, mode, bv);
    #pragma unroll
    for (int q = 0; q < 4; q++){ As[kk][c0+q]=av[q]; Bs[r][k0+q]=bv[q]; }
    __syncthreads();
    #pragma unroll
    for (int m = 0; m < 16; m++){
      float a[4], b[4];
      #pragma unroll
      for (int i = 0; i < 4; i++) a[i] = As[m][ty*4+i];
      #pragma unroll
      for (int j = 0; j < 4; j++) b[j] = Bs[tx*4+j][m];
      #pragma unroll
      for (int i = 0; i < 4; i++)
        #pragma unroll
        for (int j = 0; j < 4; j++)
          acc[i][j] += a[i]*b[j];
    }
    __syncthreads();
  }
  #pragma unroll
  for (int i = 0; i < 4; i++){
    ushort4 o;
    o.x=f2bf(acc[i][0]); o.y=f2bf(acc[i][1]); o.z=f2bf(acc[i][2]); o.w=f2bf(acc[i][3]);
    *reinterpret_cast<ushort4*>(C + (size_t)(bm*64+ty*4+i)*DIM + bn*64 + tx*4) = o;
  }
}

// ---- C[i,n] = sum_k A[i,k]*B[k,n] ; A mode-typed [Mx256], B bf16 ws [256x256], C bf16 ----
__global__ __launch_bounds__(256) void gemm_ab_mixed(const int* __restrict__ mode_p,
    const void* __restrict__ A, const bf16_t* __restrict__ B, bf16_t* __restrict__ C){
  int mode = *mode_p;
  __shared__ float As[64][17];
  __shared__ float Bs[16][68];
  const int t  = threadIdx.x;
  const int r  = t >> 2;           // 0..63
  const int k0 = (t & 3) << 2;     // 0,4,8,12
  const int kk = t >> 4;           // 0..15
  const int c0 = (t & 15) << 2;    // 0..60
  const int tx = t & 15, ty = t >> 4;
  const int bm = blockIdx.x, bn = blockIdx.y;
  float acc[4][4] = {};
  for (int kt = 0; kt < DIM; kt += 16){
    float av[4], bv[4];
    ld4(A, (size_t)(bm*64+r)*DIM + kt + k0, mode, av);
    ld4(B, (size_t)(kt+kk)*DIM + bn*64 + c0, 0, bv);
    #pragma unroll
    for (int q = 0; q < 4; q++){ As[r][k0+q]=av[q]; Bs[kk][c0+q]=bv[q]; }
    __syncthreads();
    #pragma unroll
    for (int k = 0; k < 16; k++){
      float a[4], b[4];
      #pragma unroll
      for (int i = 0; i < 4; i++) a[i] = As[ty*4+i][k];
      #pragma unroll
      for (int j = 0; j < 4; j++) b[j] = Bs[k][tx*4+j];
      #pragma unroll
      for (int i = 0; i < 4; i++)
        #pragma unroll
        for (int j = 0; j < 4; j++)
          acc[i][j] += a[i]*b[j];
    }
    __syncthreads();
  }
  #pragma unroll
  for (int i = 0; i < 4; i++){
    ushort4 o;
    o.x=f2bf(acc[i][0]); o.y=f2bf(acc[i][1]); o.z=f2bf(acc[i][2]); o.w=f2bf(acc[i][3]);
    *reinterpret_cast<ushort4*>(C + (size_t)(bm*64+ty*4+i)*DIM + bn*64 + tx*4) = o;
  }
}

// ---- fully fused: block-diag attention + out-projection (Pt matvec) + residual + LN ----
// One wave per A-row; lane L owns dims {4L..4L+3}. Grid must be exactly NA/4 blocks.
// Qp/Kp/Vp: qws/kws/vws==1 -> bf16 workspace, else mode dtype. Pt is bf16 [k][d].
// X, bout, g, bb mode dtype. out: mode dtype, at element offset out_off.
__global__ __launch_bounds__(256) void attn_fused(const int* __restrict__ mode_p,
    const void* __restrict__ Qp, int qws, const void* __restrict__ Kp, int kws,
    const void* __restrict__ Vp, int vws,
    const void* __restrict__ posA, const void* __restrict__ posB,
    const int* __restrict__ batchA, const int* __restrict__ startB,
    const bf16_t* __restrict__ Pt,
    const void* __restrict__ X, const void* __restrict__ bo,
    const void* __restrict__ g, const void* __restrict__ bb,
    void* __restrict__ out, int out_off, int NA, int NK){
  int mode = *mode_p;
  int qf = qws ? 0 : mode, kf = kws ? 0 : mode, vf = vws ? 0 : mode;
  __shared__ float ctx_s[4][DIM];
  const int wl   = threadIdx.x >> 6;          // wave in block
  const int lane = threadIdx.x & 63;
  const int w    = blockIdx.x * 4 + wl;       // A-row
  int b = batchA[w]; b = max(0, min(b, NB-1));
  int j0 = startB[b], j1 = startB[b+1];
  j0 = max(0, min(j0, NK)); j1 = max(j0, min(j1, NK));

  float q[4];  ld4(Qp, (size_t)w*DIM + 4*lane, qf, q);
  float ax = ld1(posA, (size_t)w*3+0, mode);
  float ay = ld1(posA, (size_t)w*3+1, mode);
  float az = ld1(posA, (size_t)w*3+2, mode);
  const bool sameKV = (Kp == Vp) && (kf == vf);

  float m = -3.0e38f, s = 0.f, c[4] = {0.f,0.f,0.f,0.f};
  for (int j = j0; j < j1; j++){
    float kv[4]; ld4(Kp, (size_t)j*DIM + 4*lane, kf, kv);
    float p = wave_sum(q[0]*kv[0] + q[1]*kv[1] + q[2]*kv[2] + q[3]*kv[3]);
    float dx = ax - ld1(posB, (size_t)j*3+0, mode);
    float dy = ay - ld1(posB, (size_t)j*3+1, mode);
    float dz = az - ld1(posB, (size_t)j*3+2, mode);
    float dist  = sqrtf(fmaxf(dx*dx + dy*dy + dz*dz, 1e-12f));
    float score = p * 0.0625f + __expf(-0.1f*dist);
    float mn = fmaxf(m, score);
    float f  = __expf(m - mn);
    float wj = __expf(score - mn);
    s = s*f + wj;
    float vv[4];
    if (sameKV){ vv[0]=kv[0]; vv[1]=kv[1]; vv[2]=kv[2]; vv[3]=kv[3]; }
    else ld4(Vp, (size_t)j*DIM + 4*lane, vf, vv);
    #pragma unroll
    for (int t2 = 0; t2 < 4; t2++) c[t2] = c[t2]*f + wj*vv[t2];
    m = mn;
  }
  float inv = (s > 0.f) ? 1.0f/s : 0.f;
  #pragma unroll
  for (int t2 = 0; t2 < 4; t2++) ctx_s[wl][4*lane + t2] = c[t2]*inv;
  __syncthreads();   // grid is exact (NA % 4 == 0): every wave reaches this

  // y[d] = sum_k Pt[k][d] * ctx[k], d = 4*lane + t
  float y[4] = {0.f,0.f,0.f,0.f};
  for (int k = 0; k < DIM; k++){
    float cs = ctx_s[wl][k];                 // LDS broadcast
    ushort4 pr = *reinterpret_cast<const ushort4*>(Pt + (size_t)k*DIM + 4*lane);
    y[0] += cs * bf2f(pr.x);
    y[1] += cs * bf2f(pr.y);
    y[2] += cs * bf2f(pr.z);
    y[3] += cs * bf2f(pr.w);
  }
  // residual + LN
  float xv[4], bov[4], gv[4], bbv[4];
  ld4(X,  (size_t)w*DIM + 4*lane, mode, xv);
  ld4(bo, (size_t)4*lane,         mode, bov);
  ld4(g,  (size_t)4*lane,         mode, gv);
  ld4(bb, (size_t)4*lane,         mode, bbv);
  float v[4], sum = 0.f, ssq = 0.f;
  #pragma unroll
  for (int t2 = 0; t2 < 4; t2++){
    v[t2] = xv[t2] + y[t2] + bov[t2];
    sum += v[t2]; ssq += v[t2]*v[t2];
  }
  sum = wave_sum(sum); ssq = wave_sum(ssq);
  float mu  = sum * (1.0f/DIM);
  float var = ssq * (1.0f/DIM) - mu*mu;
  float rr  = rsqrtf(fmaxf(var, 0.f) + 1e-5f);
  if (mode){
    float4 o;
    o.x = (v[0]-mu)*rr*gv[0] + bbv[0];
    o.y = (v[1]-mu)*rr*gv[1] + bbv[1];
    o.z = (v[2]-mu)*rr*gv[2] + bbv[2];
    o.w = (v[3]-mu)*rr*gv[3] + bbv[3];
    *reinterpret_cast<float4*>((float*)out + (size_t)out_off + (size_t)w*DIM + 4*lane) = o;
  } else {
    ushort4 o;
    o.x = f2bf((v[0]-mu)*rr*gv[0] + bbv[0]);
    o.y = f2bf((v[1]-mu)*rr*gv[1] + bbv[1]);
    o.z = f2bf((v[2]-mu)*rr*gv[2] + bbv[2]);
    o.w = f2bf((v[3]-mu)*rr*gv[3] + bbv[3]);
    *reinterpret_cast<ushort4*>((bf16_t*)out + (size_t)out_off + (size_t)w*DIM + 4*lane) = o;
  }
}

extern "C" void kernel_launch(void* const* d_in, const int* in_sizes, int n_in,
                              void* d_out, int out_size, void* d_ws, size_t ws_size,
                              hipStream_t stream){
  const void* lig      = d_in[0];
  const void* pro      = d_in[1];
  const void* lig_pos  = d_in[2];
  const void* pro_pos  = d_in[3];
  const int*  lig_batch= (const int*)d_in[4];
  const int*  pro_batch= (const int*)d_in[5];
  const void* Wq_lig   = d_in[6];
  const void* Wk_pro   = d_in[7];
  const void* Wv_pro   = d_in[8];
  const void* Wq_pro   = d_in[9];
  const void* Wk_lig   = d_in[10];
  const void* Wv_lig   = d_in[11];
  const void* Wout_lig = d_in[12];
  const void* bout_lig = d_in[13];
  const void* Wout_pro = d_in[14];
  const void* bout_pro = d_in[15];
  const void* g_lig    = d_in[16];
  const void* b_lig    = d_in[17];
  const void* g_pro    = d_in[18];
  const void* b_pro    = d_in[19];

  // ws: ints [0..127] then bf16 region. Total ~2.6 MB.
  int* ib        = (int*)d_ws;
  int* mode_flag = ib + 0;
  int* lig_start = ib + 16;   // 33 ints
  int* pro_start = ib + 56;   // 33 ints
  bf16_t* wsb = ((bf16_t*)d_ws) + 256;
  bf16_t* A1  = wsb;                       // Wq_lig^T @ Wk_pro   [256x256]
  bf16_t* B2  = A1 + DIM*DIM;              // Wk_lig^T @ Wq_pro   [256x256]
  bf16_t* PtL = B2 + DIM*DIM;              // (Wout_lig@Wv_pro)^T [k][d]
  bf16_t* PtP = PtL + DIM*DIM;             // (Wout_pro@Wv_lig)^T [k][d]
  bf16_t* T_lig = PtP + DIM*DIM;           // lig @ A1  [2048x256]
  bf16_t* G     = T_lig + (size_t)NLr*DIM; // lig @ B2  [2048x256]

  hipLaunchKernelGGL(detect_kernel, dim3(1), dim3(256), 0, stream,
                     lig, in_sizes[0], mode_flag);
  hipLaunchKernelGGL(bounds_kernel, dim3(1), dim3(64), 0, stream,
                     lig_batch, pro_batch, lig_start, pro_start);

  dim3 blk(256), gw(4,4), gl(NLr/64, 4);
  // A1[m,c] = sum_d Wq_lig[d,m] Wk_pro[d,c]
  hipLaunchKernelGGL(wprod_atb,  gw, blk, 0, stream, mode_flag, Wq_lig, Wk_pro, A1);
  // B2[m,k] = sum_d Wk_lig[d,m] Wq_pro[d,k]
  hipLaunchKernelGGL(wprod_atb,  gw, blk, 0, stream, mode_flag, Wk_lig, Wq_pro, B2);
  // PtL[k,d] = sum_m Wv_pro[m,k] Wout_lig[d,m]
  hipLaunchKernelGGL(wprod_atbt, gw, blk, 0, stream, mode_flag, Wv_pro, Wout_lig, PtL);
  // PtP[k,d] = sum_m Wv_lig[m,k] Wout_pro[d,m]
  hipLaunchKernelGGL(wprod_atbt, gw, blk, 0, stream, mode_flag, Wv_lig, Wout_pro, PtP);
  // T_lig = lig @ A1 ;  G = lig @ B2
  hipLaunchKernelGGL(gemm_ab_mixed, gl, blk, 0, stream, mode_flag, lig, A1, T_lig);
  hipLaunchKernelGGL(gemm_ab_mixed, gl, blk, 0, stream, mode_flag, lig, B2, G);

  // ligand <- protein: q=T_lig(ws), K=V=pro(input), out rows [0..NL)
  hipLaunchKernelGGL(attn_fused, dim3(NLr/4), blk, 0, stream, mode_flag,
                     (const void*)T_lig, 1, pro, 0, pro, 0,
                     lig_pos, pro_pos, lig_batch, pro_start, PtL,
                     lig, bout_lig, g_lig, b_lig, d_out, 0, NLr, NPr);
  // protein <- ligand: q=pro(input), K=G(ws), V=lig(input), out rows [NL..NL+NP)
  hipLaunchKernelGGL(attn_fused, dim3(NPr/4), blk, 0, stream, mode_flag,
                     pro, 0, (const void*)G, 1, lig, 0,
                     pro_pos, lig_pos, pro_batch, lig_start, PtP,
                     pro, bout_pro, g_pro, b_pro, d_out, NLr*DIM, NPr, NLr);
}

// Round 6
// 723.853 us; speedup vs baseline: 2.0258x; 2.0258x over previous
//
#include <hip/hip_runtime.h>

static constexpr int NLr = 2048;    // ligand rows
static constexpr int NPr = 16384;   // protein rows
static constexpr int DIM = 256;     // feature dim
static constexpr int NB  = 32;      // batch count

typedef unsigned short bf16_t;

// Inputs/outputs are FP32 (proven by round4/round5 A/B: runtime-detected fp32 passed,
// hardcoded bf16 NaN'd). Workspace intermediates are bf16 (passed with absmax 0.031).

__device__ inline float bf2f(bf16_t u){
  union { unsigned int i; float f; } c; c.i = ((unsigned int)u) << 16; return c.f;
}
__device__ inline bf16_t f2bf(float f){
  union { float f; unsigned int i; } c; c.f = f;
  unsigned int x = c.i;
  return (bf16_t)((x + 0x7fffu + ((x >> 16) & 1u)) >> 16);  // RNE
}

// FMT: 1 = fp32, 0 = bf16.  idx must be a multiple of 4.
template<int FMT>
__device__ inline void ld4t(const void* p, size_t idx, float* o){
  if constexpr (FMT){
    float4 f = *reinterpret_cast<const float4*>((const float*)p + idx);
    o[0]=f.x; o[1]=f.y; o[2]=f.z; o[3]=f.w;
  } else {
    ushort4 u = *reinterpret_cast<const ushort4*>((const bf16_t*)p + idx);
    o[0]=bf2f(u.x); o[1]=bf2f(u.y); o[2]=bf2f(u.z); o[3]=bf2f(u.w);
  }
}

__device__ inline float wave_sum(float x){
  #pragma unroll
  for (int off = 32; off; off >>= 1) x += __shfl_xor(x, off, 64);
  return x;
}

// ---- batch block boundaries via binary search (batch ids are sorted) ----
__global__ void bounds_kernel(const int* __restrict__ lb, const int* __restrict__ pb,
                              int* __restrict__ ls, int* __restrict__ ps){
  int t = threadIdx.x;
  if (t <= NB){
    int lo = 0, hi = NLr;
    while (lo < hi){ int mid = (lo + hi) >> 1; if (lb[mid] < t) lo = mid + 1; else hi = mid; }
    ls[t] = lo;
    lo = 0; hi = NPr;
    while (lo < hi){ int mid = (lo + hi) >> 1; if (pb[mid] < t) lo = mid + 1; else hi = mid; }
    ps[t] = lo;
  }
}

// ---- C[i,n] = sum_k A[k,i]*B[k,n]  (A^T B), 256x256, fp32 in, bf16 out ----
__global__ __launch_bounds__(256) void wprod_atb(
    const float* __restrict__ A, const float* __restrict__ B, bf16_t* __restrict__ C){
  __shared__ float As[16][68];
  __shared__ float Bs[16][68];
  const int t  = threadIdx.x;
  const int kk = t >> 4;           // 0..15
  const int c0 = (t & 15) << 2;    // 0..60
  const int tx = t & 15, ty = t >> 4;
  const int bm = blockIdx.x, bn = blockIdx.y;
  float acc[4][4] = {};
  for (int kt = 0; kt < DIM; kt += 16){
    float av[4], bv[4];
    ld4t<1>(A, (size_t)(kt+kk)*DIM + bm*64 + c0, av);
    ld4t<1>(B, (size_t)(kt+kk)*DIM + bn*64 + c0, bv);
    #pragma unroll
    for (int q = 0; q < 4; q++){ As[kk][c0+q]=av[q]; Bs[kk][c0+q]=bv[q]; }
    __syncthreads();
    #pragma unroll
    for (int k = 0; k < 16; k++){
      float a[4], b[4];
      #pragma unroll
      for (int i = 0; i < 4; i++) a[i] = As[k][ty*4+i];
      #pragma unroll
      for (int j = 0; j < 4; j++) b[j] = Bs[k][tx*4+j];
      #pragma unroll
      for (int i = 0; i < 4; i++)
        #pragma unroll
        for (int j = 0; j < 4; j++)
          acc[i][j] += a[i]*b[j];
    }
    __syncthreads();
  }
  #pragma unroll
  for (int i = 0; i < 4; i++){
    ushort4 o;
    o.x=f2bf(acc[i][0]); o.y=f2bf(acc[i][1]); o.z=f2bf(acc[i][2]); o.w=f2bf(acc[i][3]);
    *reinterpret_cast<ushort4*>(C + (size_t)(bm*64+ty*4+i)*DIM + bn*64 + tx*4) = o;
  }
}

// ---- C[i,n] = sum_m A[m,i]*B[n,m]  (A^T B^T), 256x256, fp32 in, bf16 out ----
__global__ __launch_bounds__(256) void wprod_atbt(
    const float* __restrict__ A, const float* __restrict__ B, bf16_t* __restrict__ C){
  __shared__ float As[16][68];
  __shared__ float Bs[64][17];
  const int t  = threadIdx.x;
  const int kk = t >> 4;           // 0..15 (m-chunk for A)
  const int c0 = (t & 15) << 2;    // 0..60 (i for A)
  const int r  = t >> 2;           // 0..63 (n for B)
  const int k0 = (t & 3) << 2;     // 0..12 (m for B)
  const int tx = t & 15, ty = t >> 4;
  const int bm = blockIdx.x, bn = blockIdx.y;
  float acc[4][4] = {};
  for (int mt = 0; mt < DIM; mt += 16){
    float av[4], bv[4];
    ld4t<1>(A, (size_t)(mt+kk)*DIM + bm*64 + c0, av);
    ld4t<1>(B, (size_t)(bn*64+r)*DIM + mt + k0, bv);
    #pragma unroll
    for (int q = 0; q < 4; q++){ As[kk][c0+q]=av[q]; Bs[r][k0+q]=bv[q]; }
    __syncthreads();
    #pragma unroll
    for (int m = 0; m < 16; m++){
      float a[4], b[4];
      #pragma unroll
      for (int i = 0; i < 4; i++) a[i] = As[m][ty*4+i];
      #pragma unroll
      for (int j = 0; j < 4; j++) b[j] = Bs[tx*4+j][m];
      #pragma unroll
      for (int i = 0; i < 4; i++)
        #pragma unroll
        for (int j = 0; j < 4; j++)
          acc[i][j] += a[i]*b[j];
    }
    __syncthreads();
  }
  #pragma unroll
  for (int i = 0; i < 4; i++){
    ushort4 o;
    o.x=f2bf(acc[i][0]); o.y=f2bf(acc[i][1]); o.z=f2bf(acc[i][2]); o.w=f2bf(acc[i][3]);
    *reinterpret_cast<ushort4*>(C + (size_t)(bm*64+ty*4+i)*DIM + bn*64 + tx*4) = o;
  }
}

// ---- C[i,n] = sum_k A[i,k]*B[k,n]  (A @ B); A fp32 [Mx256], B bf16 ws; C bf16 ----
__global__ __launch_bounds__(256) void gemm_ab(
    const float* __restrict__ A, const bf16_t* __restrict__ B, bf16_t* __restrict__ C){
  __shared__ float As[64][17];
  __shared__ float Bs[16][68];
  const int t  = threadIdx.x;
  const int r  = t >> 2;           // 0..63
  const int k0 = (t & 3) << 2;     // 0,4,8,12
  const int kk = t >> 4;           // 0..15
  const int c0 = (t & 15) << 2;    // 0..60
  const int tx = t & 15, ty = t >> 4;
  const int bm = blockIdx.x, bn = blockIdx.y;
  float acc[4][4] = {};
  for (int kt = 0; kt < DIM; kt += 16){
    float av[4], bv[4];
    ld4t<1>(A, (size_t)(bm*64+r)*DIM + kt + k0, av);
    ld4t<0>(B, (size_t)(kt+kk)*DIM + bn*64 + c0, bv);
    #pragma unroll
    for (int q = 0; q < 4; q++){ As[r][k0+q]=av[q]; Bs[kk][c0+q]=bv[q]; }
    __syncthreads();
    #pragma unroll
    for (int k = 0; k < 16; k++){
      float a[4], b[4];
      #pragma unroll
      for (int i = 0; i < 4; i++) a[i] = As[ty*4+i][k];
      #pragma unroll
      for (int j = 0; j < 4; j++) b[j] = Bs[k][tx*4+j];
      #pragma unroll
      for (int i = 0; i < 4; i++)
        #pragma unroll
        for (int j = 0; j < 4; j++)
          acc[i][j] += a[i]*b[j];
    }
    __syncthreads();
  }
  #pragma unroll
  for (int i = 0; i < 4; i++){
    ushort4 o;
    o.x=f2bf(acc[i][0]); o.y=f2bf(acc[i][1]); o.z=f2bf(acc[i][2]); o.w=f2bf(acc[i][3]);
    *reinterpret_cast<ushort4*>(C + (size_t)(bm*64+ty*4+i)*DIM + bn*64 + tx*4) = o;
  }
}

// ---- fused: block-diag attention + out-projection + residual + LN; fp32 out ----
// One wave per A-row; lane L owns dims {4L..4L+3}. Grid exactly NA/4 blocks.
// QF/KF/VF: 1 = fp32 input tensor, 0 = bf16 workspace tensor.
template<int QF, int KF, int VF>
__global__ __launch_bounds__(256) void attn_fused(
    const void* __restrict__ Qp, const void* __restrict__ Kp,
    const void* __restrict__ Vp,
    const float* __restrict__ posA, const float* __restrict__ posB,
    const int* __restrict__ batchA, const int* __restrict__ startB,
    const bf16_t* __restrict__ Pt,
    const float* __restrict__ X, const float* __restrict__ bo,
    const float* __restrict__ g, const float* __restrict__ bb,
    float* __restrict__ out, int out_off, int NA, int NK){
  __shared__ float ctx_s[4][DIM];
  const int wl   = threadIdx.x >> 6;
  const int lane = threadIdx.x & 63;
  const int w    = blockIdx.x * 4 + wl;       // A-row
  int b = batchA[w]; b = max(0, min(b, NB-1));
  int j0 = startB[b], j1 = startB[b+1];
  j0 = max(0, min(j0, NK)); j1 = max(j0, min(j1, NK));

  float q[4];  ld4t<QF>(Qp, (size_t)w*DIM + 4*lane, q);
  float ax = posA[(size_t)w*3+0];
  float ay = posA[(size_t)w*3+1];
  float az = posA[(size_t)w*3+2];
  const bool sameKV = (KF == VF) && (Kp == Vp);

  float m = -3.0e38f, s = 0.f, c[4] = {0.f,0.f,0.f,0.f};
  float kv[4] = {0.f,0.f,0.f,0.f};
  float bx=0.f, by=0.f, bz=0.f;
  if (j0 < j1){
    ld4t<KF>(Kp, (size_t)j0*DIM + 4*lane, kv);
    bx = posB[(size_t)j0*3+0];
    by = posB[(size_t)j0*3+1];
    bz = posB[(size_t)j0*3+2];
  }
  for (int j = j0; j < j1; j++){
    float ckv[4] = {kv[0], kv[1], kv[2], kv[3]};
    float cbx = bx, cby = by, cbz = bz;
    int jn = j + 1;
    if (jn < j1){                       // prefetch next K-row + pos (hide L2 latency)
      ld4t<KF>(Kp, (size_t)jn*DIM + 4*lane, kv);
      bx = posB[(size_t)jn*3+0];
      by = posB[(size_t)jn*3+1];
      bz = posB[(size_t)jn*3+2];
    }
    float p = wave_sum(q[0]*ckv[0] + q[1]*ckv[1] + q[2]*ckv[2] + q[3]*ckv[3]);
    float dx = ax - cbx, dy = ay - cby, dz = az - cbz;
    float dist  = sqrtf(fmaxf(dx*dx + dy*dy + dz*dz, 1e-12f));
    float score = p * 0.0625f + __expf(-0.1f*dist);
    float mn = fmaxf(m, score);
    float f  = __expf(m - mn);
    float wj = __expf(score - mn);
    s = s*f + wj;
    float vv[4];
    if (sameKV){ vv[0]=ckv[0]; vv[1]=ckv[1]; vv[2]=ckv[2]; vv[3]=ckv[3]; }
    else ld4t<VF>(Vp, (size_t)j*DIM + 4*lane, vv);
    #pragma unroll
    for (int t2 = 0; t2 < 4; t2++) c[t2] = c[t2]*f + wj*vv[t2];
    m = mn;
  }
  float inv = (s > 0.f) ? 1.0f/s : 0.f;
  #pragma unroll
  for (int t2 = 0; t2 < 4; t2++) ctx_s[wl][4*lane + t2] = c[t2]*inv;
  __syncthreads();   // grid exact (NA % 4 == 0): every wave reaches this

  // y[d] = sum_k Pt[k][d] * ctx[k], d = 4*lane + t
  float y[4] = {0.f,0.f,0.f,0.f};
  for (int k = 0; k < DIM; k++){
    float cs = ctx_s[wl][k];                 // LDS broadcast
    ushort4 pr = *reinterpret_cast<const ushort4*>(Pt + (size_t)k*DIM + 4*lane);
    y[0] += cs * bf2f(pr.x);
    y[1] += cs * bf2f(pr.y);
    y[2] += cs * bf2f(pr.z);
    y[3] += cs * bf2f(pr.w);
  }
  // residual + LN (all fp32 operands)
  float xv[4], bov[4], gv[4], bbv[4];
  ld4t<1>(X,  (size_t)w*DIM + 4*lane, xv);
  ld4t<1>(bo, (size_t)4*lane, bov);
  ld4t<1>(g,  (size_t)4*lane, gv);
  ld4t<1>(bb, (size_t)4*lane, bbv);
  float v[4], sum = 0.f, ssq = 0.f;
  #pragma unroll
  for (int t2 = 0; t2 < 4; t2++){
    v[t2] = xv[t2] + y[t2] + bov[t2];
    sum += v[t2]; ssq += v[t2]*v[t2];
  }
  sum = wave_sum(sum); ssq = wave_sum(ssq);
  float mu  = sum * (1.0f/DIM);
  float var = ssq * (1.0f/DIM) - mu*mu;
  float rr  = rsqrtf(fmaxf(var, 0.f) + 1e-5f);
  float4 o;
  o.x = (v[0]-mu)*rr*gv[0] + bbv[0];
  o.y = (v[1]-mu)*rr*gv[1] + bbv[1];
  o.z = (v[2]-mu)*rr*gv[2] + bbv[2];
  o.w = (v[3]-mu)*rr*gv[3] + bbv[3];
  *reinterpret_cast<float4*>(out + (size_t)out_off + (size_t)w*DIM + 4*lane) = o;
}

extern "C" void kernel_launch(void* const* d_in, const int* in_sizes, int n_in,
                              void* d_out, int out_size, void* d_ws, size_t ws_size,
                              hipStream_t stream){
  const float* lig      = (const float*)d_in[0];
  const float* pro      = (const float*)d_in[1];
  const float* lig_pos  = (const float*)d_in[2];
  const float* pro_pos  = (const float*)d_in[3];
  const int*   lig_batch= (const int*)d_in[4];
  const int*   pro_batch= (const int*)d_in[5];
  const float* Wq_lig   = (const float*)d_in[6];
  const float* Wk_pro   = (const float*)d_in[7];
  const float* Wv_pro   = (const float*)d_in[8];
  const float* Wq_pro   = (const float*)d_in[9];
  const float* Wk_lig   = (const float*)d_in[10];
  const float* Wv_lig   = (const float*)d_in[11];
  const float* Wout_lig = (const float*)d_in[12];
  const float* bout_lig = (const float*)d_in[13];
  const float* Wout_pro = (const float*)d_in[14];
  const float* bout_pro = (const float*)d_in[15];
  const float* g_lig    = (const float*)d_in[16];
  const float* b_lig    = (const float*)d_in[17];
  const float* g_pro    = (const float*)d_in[18];
  const float* b_pro    = (const float*)d_in[19];

  // ws: ints then bf16 region. Total ~2.6 MB (layout proven in round 4).
  int* ib        = (int*)d_ws;
  int* lig_start = ib + 16;   // 33 ints
  int* pro_start = ib + 56;   // 33 ints
  bf16_t* wsb = ((bf16_t*)d_ws) + 256;
  bf16_t* A1  = wsb;                       // Wq_lig^T @ Wk_pro   [256x256]
  bf16_t* B2  = A1 + DIM*DIM;              // Wk_lig^T @ Wq_pro   [256x256]
  bf16_t* PtL = B2 + DIM*DIM;              // (Wout_lig@Wv_pro)^T [k][d]
  bf16_t* PtP = PtL + DIM*DIM;             // (Wout_pro@Wv_lig)^T [k][d]
  bf16_t* T_lig = PtP + DIM*DIM;           // lig @ A1  [2048x256]
  bf16_t* G     = T_lig + (size_t)NLr*DIM; // lig @ B2  [2048x256]

  float* outp = (float*)d_out;

  hipLaunchKernelGGL(bounds_kernel, dim3(1), dim3(64), 0, stream,
                     lig_batch, pro_batch, lig_start, pro_start);

  dim3 blk(256), gw(4,4), gl(NLr/64, 4);
  hipLaunchKernelGGL(wprod_atb,  gw, blk, 0, stream, Wq_lig, Wk_pro, A1);
  hipLaunchKernelGGL(wprod_atb,  gw, blk, 0, stream, Wk_lig, Wq_pro, B2);
  hipLaunchKernelGGL(wprod_atbt, gw, blk, 0, stream, Wv_pro, Wout_lig, PtL);
  hipLaunchKernelGGL(wprod_atbt, gw, blk, 0, stream, Wv_lig, Wout_pro, PtP);
  hipLaunchKernelGGL(gemm_ab, gl, blk, 0, stream, lig, A1, T_lig);
  hipLaunchKernelGGL(gemm_ab, gl, blk, 0, stream, lig, B2, G);

  // ligand <- protein: q = T_lig (bf16 ws), K = V = pro (fp32 input)
  hipLaunchKernelGGL((attn_fused<0,1,1>), dim3(NLr/4), blk, 0, stream,
                     (const void*)T_lig, (const void*)pro, (const void*)pro,
                     lig_pos, pro_pos, lig_batch, pro_start, PtL,
                     lig, bout_lig, g_lig, b_lig, outp, 0, NLr, NPr);
  // protein <- ligand: q = pro (fp32 input), K = G (bf16 ws), V = lig (fp32 input)
  hipLaunchKernelGGL((attn_fused<1,0,1>), dim3(NPr/4), blk, 0, stream,
                     (const void*)pro, (const void*)G, (const void*)lig,
                     pro_pos, lig_pos, pro_batch, lig_start, PtP,
                     pro, bout_pro, g_pro, b_pro, outp, NLr*DIM, NPr, NLr);
}

// Round 7
// 612.544 us; speedup vs baseline: 2.3940x; 1.1817x over previous
//
#include <hip/hip_runtime.h>

static constexpr int NLr = 2048;    // ligand rows
static constexpr int NPr = 16384;   // protein rows
static constexpr int DIM = 256;     // feature dim
static constexpr int NB  = 32;      // batch count

typedef unsigned short bf16_t;

// Inputs/outputs are FP32 (proven round4/5 A/B). Workspace intermediates bf16.

__device__ inline float bf2f(bf16_t u){
  union { unsigned int i; float f; } c; c.i = ((unsigned int)u) << 16; return c.f;
}
__device__ inline bf16_t f2bf(float f){
  union { float f; unsigned int i; } c; c.f = f;
  unsigned int x = c.i;
  return (bf16_t)((x + 0x7fffu + ((x >> 16) & 1u)) >> 16);  // RNE
}

// FMT: 1 = fp32, 0 = bf16. idx multiple of 4.
template<int FMT>
__device__ inline void ld4t(const void* p, size_t idx, float* o){
  if constexpr (FMT){
    float4 f = *reinterpret_cast<const float4*>((const float*)p + idx);
    o[0]=f.x; o[1]=f.y; o[2]=f.z; o[3]=f.w;
  } else {
    ushort4 u = *reinterpret_cast<const ushort4*>((const bf16_t*)p + idx);
    o[0]=bf2f(u.x); o[1]=bf2f(u.y); o[2]=bf2f(u.z); o[3]=bf2f(u.w);
  }
}

__device__ inline float wave_sum(float x){
  #pragma unroll
  for (int off = 32; off; off >>= 1) x += __shfl_xor(x, off, 64);
  return x;
}

// ---- batch block boundaries via binary search (batch ids are sorted) ----
__global__ void bounds_kernel(const int* __restrict__ lb, const int* __restrict__ pb,
                              int* __restrict__ ls, int* __restrict__ ps){
  int t = threadIdx.x;
  if (t <= NB){
    int lo = 0, hi = NLr;
    while (lo < hi){ int mid = (lo + hi) >> 1; if (lb[mid] < t) lo = mid + 1; else hi = mid; }
    ls[t] = lo;
    lo = 0; hi = NPr;
    while (lo < hi){ int mid = (lo + hi) >> 1; if (pb[mid] < t) lo = mid + 1; else hi = mid; }
    ps[t] = lo;
  }
}

// ---- C[i,n] = sum_k A[k,i]*B[k,n]  (A^T B), 256x256, fp32 in, bf16 out ----
__global__ __launch_bounds__(256) void wprod_atb(
    const float* __restrict__ A, const float* __restrict__ B, bf16_t* __restrict__ C){
  __shared__ float As[16][68];
  __shared__ float Bs[16][68];
  const int t  = threadIdx.x;
  const int kk = t >> 4;
  const int c0 = (t & 15) << 2;
  const int tx = t & 15, ty = t >> 4;
  const int bm = blockIdx.x, bn = blockIdx.y;
  float acc[4][4] = {};
  for (int kt = 0; kt < DIM; kt += 16){
    float av[4], bv[4];
    ld4t<1>(A, (size_t)(kt+kk)*DIM + bm*64 + c0, av);
    ld4t<1>(B, (size_t)(kt+kk)*DIM + bn*64 + c0, bv);
    #pragma unroll
    for (int q = 0; q < 4; q++){ As[kk][c0+q]=av[q]; Bs[kk][c0+q]=bv[q]; }
    __syncthreads();
    #pragma unroll
    for (int k = 0; k < 16; k++){
      float a[4], b[4];
      #pragma unroll
      for (int i = 0; i < 4; i++) a[i] = As[k][ty*4+i];
      #pragma unroll
      for (int j = 0; j < 4; j++) b[j] = Bs[k][tx*4+j];
      #pragma unroll
      for (int i = 0; i < 4; i++)
        #pragma unroll
        for (int j = 0; j < 4; j++)
          acc[i][j] += a[i]*b[j];
    }
    __syncthreads();
  }
  #pragma unroll
  for (int i = 0; i < 4; i++){
    ushort4 o;
    o.x=f2bf(acc[i][0]); o.y=f2bf(acc[i][1]); o.z=f2bf(acc[i][2]); o.w=f2bf(acc[i][3]);
    *reinterpret_cast<ushort4*>(C + (size_t)(bm*64+ty*4+i)*DIM + bn*64 + tx*4) = o;
  }
}

// ---- C[i,n] = sum_m A[m,i]*B[n,m]  (A^T B^T), 256x256, fp32 in, bf16 out ----
__global__ __launch_bounds__(256) void wprod_atbt(
    const float* __restrict__ A, const float* __restrict__ B, bf16_t* __restrict__ C){
  __shared__ float As[16][68];
  __shared__ float Bs[64][17];
  const int t  = threadIdx.x;
  const int kk = t >> 4;
  const int c0 = (t & 15) << 2;
  const int r  = t >> 2;
  const int k0 = (t & 3) << 2;
  const int tx = t & 15, ty = t >> 4;
  const int bm = blockIdx.x, bn = blockIdx.y;
  float acc[4][4] = {};
  for (int mt = 0; mt < DIM; mt += 16){
    float av[4], bv[4];
    ld4t<1>(A, (size_t)(mt+kk)*DIM + bm*64 + c0, av);
    ld4t<1>(B, (size_t)(bn*64+r)*DIM + mt + k0, bv);
    #pragma unroll
    for (int q = 0; q < 4; q++){ As[kk][c0+q]=av[q]; Bs[r][k0+q]=bv[q]; }
    __syncthreads();
    #pragma unroll
    for (int m = 0; m < 16; m++){
      float a[4], b[4];
      #pragma unroll
      for (int i = 0; i < 4; i++) a[i] = As[m][ty*4+i];
      #pragma unroll
      for (int j = 0; j < 4; j++) b[j] = Bs[tx*4+j][m];
      #pragma unroll
      for (int i = 0; i < 4; i++)
        #pragma unroll
        for (int j = 0; j < 4; j++)
          acc[i][j] += a[i]*b[j];
    }
    __syncthreads();
  }
  #pragma unroll
  for (int i = 0; i < 4; i++){
    ushort4 o;
    o.x=f2bf(acc[i][0]); o.y=f2bf(acc[i][1]); o.z=f2bf(acc[i][2]); o.w=f2bf(acc[i][3]);
    *reinterpret_cast<ushort4*>(C + (size_t)(bm*64+ty*4+i)*DIM + bn*64 + tx*4) = o;
  }
}

// ---- C[i,n] = sum_k A[i,k]*B[k,n]  (A @ B); A fp32 [Mx256], B bf16 ws; C bf16 ----
__global__ __launch_bounds__(256) void gemm_ab(
    const float* __restrict__ A, const bf16_t* __restrict__ B, bf16_t* __restrict__ C){
  __shared__ float As[64][17];
  __shared__ float Bs[16][68];
  const int t  = threadIdx.x;
  const int r  = t >> 2;
  const int k0 = (t & 3) << 2;
  const int kk = t >> 4;
  const int c0 = (t & 15) << 2;
  const int tx = t & 15, ty = t >> 4;
  const int bm = blockIdx.x, bn = blockIdx.y;
  float acc[4][4] = {};
  for (int kt = 0; kt < DIM; kt += 16){
    float av[4], bv[4];
    ld4t<1>(A, (size_t)(bm*64+r)*DIM + kt + k0, av);
    ld4t<0>(B, (size_t)(kt+kk)*DIM + bn*64 + c0, bv);
    #pragma unroll
    for (int q = 0; q < 4; q++){ As[r][k0+q]=av[q]; Bs[kk][c0+q]=bv[q]; }
    __syncthreads();
    #pragma unroll
    for (int k = 0; k < 16; k++){
      float a[4], b[4];
      #pragma unroll
      for (int i = 0; i < 4; i++) a[i] = As[ty*4+i][k];
      #pragma unroll
      for (int j = 0; j < 4; j++) b[j] = Bs[k][tx*4+j];
      #pragma unroll
      for (int i = 0; i < 4; i++)
        #pragma unroll
        for (int j = 0; j < 4; j++)
          acc[i][j] += a[i]*b[j];
    }
    __syncthreads();
  }
  #pragma unroll
  for (int i = 0; i < 4; i++){
    ushort4 o;
    o.x=f2bf(acc[i][0]); o.y=f2bf(acc[i][1]); o.z=f2bf(acc[i][2]); o.w=f2bf(acc[i][3]);
    *reinterpret_cast<ushort4*>(C + (size_t)(bm*64+ty*4+i)*DIM + bn*64 + tx*4) = o;
  }
}

// ---- tiled fused attention: RT rows/block share LDS-staged K/V chunks ----
// lane-per-key scores (no per-key wave reduction), lane-per-dim ctx accumulate,
// fused out-projection + residual + LN. QF/KF/VF: 1=fp32, 0=bf16 source.
template<int QF, int KF, int VF, int SAMEKV, int RT>
__global__ __launch_bounds__(256) void attn_tiled(
    const void* __restrict__ Qp, const void* __restrict__ Kp, const void* __restrict__ Vp,
    const float* __restrict__ posA, const float* __restrict__ posB,
    const int* __restrict__ batchA, const int* __restrict__ startB,
    const bf16_t* __restrict__ Pt,
    const float* __restrict__ X, const float* __restrict__ bo,
    const float* __restrict__ g, const float* __restrict__ bb,
    float* __restrict__ out, int out_off, int NK){
  constexpr int CK   = 32;        // keys per chunk
  constexpr int RPW  = RT/4;      // rows per wave
  constexpr int NPASS= RPW/2;     // score passes (2 rows per pass via wave halves)
  __shared__ float  qs[RT][DIM];          // q tile, later reused as ctx buffer
  __shared__ bf16_t Ks[DIM][CK+2];        // stride 34: score reads 2-way, ctx reads 2-way
  __shared__ bf16_t Vs[DIM][CK+2];
  __shared__ float  Ps[RT][CK];
  __shared__ float  pbs[3][CK];
  __shared__ float  alph[RT];
  __shared__ float  srow_s[RT];

  const int t = threadIdx.x, wl = t >> 6, lane = t & 63;
  const int row0 = blockIdx.x * RT;

  // stage q tile (coalesced)
  for (int idx = t; idx < RT*64; idx += 256){
    int r = idx >> 6, d0 = (idx & 63) << 2;
    float qv[4]; ld4t<QF>(Qp, (size_t)(row0 + r)*DIM + d0, qv);
    *reinterpret_cast<float4*>(&qs[r][d0]) = make_float4(qv[0],qv[1],qv[2],qv[3]);
  }

  // per-lane score-row metadata (row = wl*RPW + 2*p + half)
  const int half = lane >> 5;
  int   sj0[NPASS], sj1[NPASS];
  float ax[NPASS], ay[NPASS], az[NPASS];
  float mrow[NPASS], srw[NPASS];
  #pragma unroll
  for (int p = 0; p < NPASS; p++){
    int grow = row0 + wl*RPW + 2*p + half;
    int b = batchA[grow];
    sj0[p] = startB[b]; sj1[p] = startB[b+1];
    ax[p] = posA[(size_t)grow*3+0];
    ay[p] = posA[(size_t)grow*3+1];
    az[p] = posA[(size_t)grow*3+2];
    mrow[p] = -3.0e38f; srw[p] = 0.f;
  }
  float ctx[RPW][4] = {};

  const int b_lo = batchA[row0], b_hi = batchA[row0 + RT - 1];
  const int kmin = startB[b_lo], kmax = startB[b_hi + 1];

  for (int c0 = kmin; c0 < kmax; c0 += CK){
    const int n = min(CK, kmax - c0);
    // ---- stage K (and V) chunk + posB into LDS ----
    {
      int jj = t >> 3;            // 0..31
      int dq = (t & 7) << 2;      // 0,4,...,28
      if (jj < n){
        #pragma unroll
        for (int ii = 0; ii < 8; ii++){
          int d = dq + (ii << 5);
          float kvv[4]; ld4t<KF>(Kp, (size_t)(c0+jj)*DIM + d, kvv);
          Ks[d+0][jj]=f2bf(kvv[0]); Ks[d+1][jj]=f2bf(kvv[1]);
          Ks[d+2][jj]=f2bf(kvv[2]); Ks[d+3][jj]=f2bf(kvv[3]);
          if constexpr (!SAMEKV){
            float vvv[4]; ld4t<VF>(Vp, (size_t)(c0+jj)*DIM + d, vvv);
            Vs[d+0][jj]=f2bf(vvv[0]); Vs[d+1][jj]=f2bf(vvv[1]);
            Vs[d+2][jj]=f2bf(vvv[2]); Vs[d+3][jj]=f2bf(vvv[3]);
          }
        }
      }
      if (t < 3*CK){
        int axis = t / CK, j2 = t % CK;
        pbs[axis][j2] = (j2 < n) ? posB[(size_t)(c0+j2)*3 + axis] : 0.f;
      }
    }
    __syncthreads();

    // ---- score phase: lane-per-key ----
    const int j  = lane & 31;
    const int jg = c0 + j;
    #pragma unroll
    for (int p = 0; p < NPASS; p++){
      int r = wl*RPW + 2*p + half;
      float sc = 0.f;
      #pragma unroll 8
      for (int d0 = 0; d0 < DIM; d0 += 4){
        float4 qv = *reinterpret_cast<const float4*>(&qs[r][d0]);
        sc += qv.x * bf2f(Ks[d0+0][j]);
        sc += qv.y * bf2f(Ks[d0+1][j]);
        sc += qv.z * bf2f(Ks[d0+2][j]);
        sc += qv.w * bf2f(Ks[d0+3][j]);
      }
      bool valid = (j < n) && (jg >= sj0[p]) && (jg < sj1[p]);
      float dx = ax[p]-pbs[0][j], dy = ay[p]-pbs[1][j], dz = az[p]-pbs[2][j];
      float dist = sqrtf(fmaxf(dx*dx + dy*dy + dz*dz, 1e-12f));
      sc = sc*0.0625f + __expf(-0.1f*dist);
      sc = valid ? sc : -1.0e30f;          // also discards NaN from stale LDS lanes
      float cm = sc;
      #pragma unroll
      for (int off = 1; off < 32; off <<= 1) cm = fmaxf(cm, __shfl_xor(cm, off, 64));
      float mnew = fmaxf(mrow[p], cm);
      float aa = __expf(mrow[p] - mnew);
      float w  = valid ? __expf(sc - mnew) : 0.f;
      Ps[r][j] = w;
      float ws = w;
      #pragma unroll
      for (int off = 1; off < 32; off <<= 1) ws += __shfl_xor(ws, off, 64);
      srw[p]  = srw[p]*aa + ws;
      mrow[p] = mnew;
      if ((lane & 31) == 0) alph[r] = aa;
    }
    __syncthreads();

    // ---- ctx phase: lane-per-dim (d = lane + 64i), V from LDS ----
    #pragma unroll
    for (int rr = 0; rr < RPW; rr++){
      float a = alph[wl*RPW + rr];
      #pragma unroll
      for (int i = 0; i < 4; i++) ctx[rr][i] *= a;
    }
    for (int j2 = 0; j2 < n; j2++){
      float v0, v1, v2, v3;
      if constexpr (SAMEKV){
        v0 = bf2f(Ks[lane][j2]);     v1 = bf2f(Ks[lane+64][j2]);
        v2 = bf2f(Ks[lane+128][j2]); v3 = bf2f(Ks[lane+192][j2]);
      } else {
        v0 = bf2f(Vs[lane][j2]);     v1 = bf2f(Vs[lane+64][j2]);
        v2 = bf2f(Vs[lane+128][j2]); v3 = bf2f(Vs[lane+192][j2]);
      }
      #pragma unroll
      for (int rr = 0; rr < RPW; rr++){
        float w = Ps[wl*RPW + rr][j2];
        ctx[rr][0] += w*v0; ctx[rr][1] += w*v1;
        ctx[rr][2] += w*v2; ctx[rr][3] += w*v3;
      }
    }
    __syncthreads();
  }

  // ---- publish s, normalize ctx into qs ----
  #pragma unroll
  for (int p = 0; p < NPASS; p++){
    int r = wl*RPW + 2*p + half;
    if ((lane & 31) == 0) srow_s[r] = srw[p];
  }
  __syncthreads();
  #pragma unroll
  for (int rr = 0; rr < RPW; rr++){
    int r = wl*RPW + rr;
    float s = srow_s[r];
    float inv = (s > 0.f) ? 1.0f/s : 0.f;
    #pragma unroll
    for (int i = 0; i < 4; i++) qs[r][lane + 64*i] = ctx[rr][i]*inv;
  }
  __syncthreads();

  // ---- out-projection + residual + LN, one row at a time per wave ----
  #pragma unroll
  for (int rr = 0; rr < RPW; rr++){
    int r = wl*RPW + rr, grow = row0 + r;
    float y[4] = {0.f,0.f,0.f,0.f};
    for (int k = 0; k < DIM; k++){
      float cs = qs[r][k];
      ushort4 pr = *reinterpret_cast<const ushort4*>(Pt + (size_t)k*DIM + 4*lane);
      y[0] += cs*bf2f(pr.x); y[1] += cs*bf2f(pr.y);
      y[2] += cs*bf2f(pr.z); y[3] += cs*bf2f(pr.w);
    }
    float xv[4], bov[4], gv[4], bbv[4];
    ld4t<1>(X,  (size_t)grow*DIM + 4*lane, xv);
    ld4t<1>(bo, (size_t)4*lane, bov);
    ld4t<1>(g,  (size_t)4*lane, gv);
    ld4t<1>(bb, (size_t)4*lane, bbv);
    float v[4], sum = 0.f, ssq = 0.f;
    #pragma unroll
    for (int i = 0; i < 4; i++){
      v[i] = xv[i] + y[i] + bov[i];
      sum += v[i]; ssq += v[i]*v[i];
    }
    sum = wave_sum(sum); ssq = wave_sum(ssq);
    float mu  = sum * (1.0f/DIM);
    float var = ssq * (1.0f/DIM) - mu*mu;
    float rr2 = rsqrtf(fmaxf(var, 0.f) + 1e-5f);
    float4 o;
    o.x = (v[0]-mu)*rr2*gv[0] + bbv[0];
    o.y = (v[1]-mu)*rr2*gv[1] + bbv[1];
    o.z = (v[2]-mu)*rr2*gv[2] + bbv[2];
    o.w = (v[3]-mu)*rr2*gv[3] + bbv[3];
    *reinterpret_cast<float4*>(out + (size_t)out_off + (size_t)grow*DIM + 4*lane) = o;
  }
}

extern "C" void kernel_launch(void* const* d_in, const int* in_sizes, int n_in,
                              void* d_out, int out_size, void* d_ws, size_t ws_size,
                              hipStream_t stream){
  const float* lig      = (const float*)d_in[0];
  const float* pro      = (const float*)d_in[1];
  const float* lig_pos  = (const float*)d_in[2];
  const float* pro_pos  = (const float*)d_in[3];
  const int*   lig_batch= (const int*)d_in[4];
  const int*   pro_batch= (const int*)d_in[5];
  const float* Wq_lig   = (const float*)d_in[6];
  const float* Wk_pro   = (const float*)d_in[7];
  const float* Wv_pro   = (const float*)d_in[8];
  const float* Wq_pro   = (const float*)d_in[9];
  const float* Wk_lig   = (const float*)d_in[10];
  const float* Wv_lig   = (const float*)d_in[11];
  const float* Wout_lig = (const float*)d_in[12];
  const float* bout_lig = (const float*)d_in[13];
  const float* Wout_pro = (const float*)d_in[14];
  const float* bout_pro = (const float*)d_in[15];
  const float* g_lig    = (const float*)d_in[16];
  const float* b_lig    = (const float*)d_in[17];
  const float* g_pro    = (const float*)d_in[18];
  const float* b_pro    = (const float*)d_in[19];

  // ws: ints then bf16 region. ~2.6 MB (layout proven round 4/6).
  int* ib        = (int*)d_ws;
  int* lig_start = ib + 16;
  int* pro_start = ib + 56;
  bf16_t* wsb = ((bf16_t*)d_ws) + 256;
  bf16_t* A1  = wsb;                       // Wq_lig^T @ Wk_pro   [256x256]
  bf16_t* B2  = A1 + DIM*DIM;              // Wk_lig^T @ Wq_pro   [256x256]
  bf16_t* PtL = B2 + DIM*DIM;              // (Wout_lig@Wv_pro)^T [k][d]
  bf16_t* PtP = PtL + DIM*DIM;             // (Wout_pro@Wv_lig)^T [k][d]
  bf16_t* T_lig = PtP + DIM*DIM;           // lig @ A1  [2048x256]
  bf16_t* G     = T_lig + (size_t)NLr*DIM; // lig @ B2  [2048x256]

  float* outp = (float*)d_out;

  hipLaunchKernelGGL(bounds_kernel, dim3(1), dim3(64), 0, stream,
                     lig_batch, pro_batch, lig_start, pro_start);

  dim3 blk(256), gw(4,4), gl(NLr/64, 4);
  hipLaunchKernelGGL(wprod_atb,  gw, blk, 0, stream, Wq_lig, Wk_pro, A1);
  hipLaunchKernelGGL(wprod_atb,  gw, blk, 0, stream, Wk_lig, Wq_pro, B2);
  hipLaunchKernelGGL(wprod_atbt, gw, blk, 0, stream, Wv_pro, Wout_lig, PtL);
  hipLaunchKernelGGL(wprod_atbt, gw, blk, 0, stream, Wv_lig, Wout_pro, PtP);
  hipLaunchKernelGGL(gemm_ab, gl, blk, 0, stream, lig, A1, T_lig);
  hipLaunchKernelGGL(gemm_ab, gl, blk, 0, stream, lig, B2, G);

  // ligand <- protein: q=T_lig (bf16 ws), K=V=pro (fp32). RT=8 -> 256 blocks.
  hipLaunchKernelGGL((attn_tiled<0,1,1,1,8>), dim3(NLr/8), blk, 0, stream,
                     (const void*)T_lig, (const void*)pro, (const void*)pro,
                     lig_pos, pro_pos, lig_batch, pro_start, PtL,
                     lig, bout_lig, g_lig, b_lig, outp, 0, NPr);
  // protein <- ligand: q=pro (fp32), K=G (bf16 ws), V=lig (fp32). RT=16 -> 1024 blocks.
  hipLaunchKernelGGL((attn_tiled<1,0,1,0,16>), dim3(NPr/16), blk, 0, stream,
                     (const void*)pro, (const void*)G, (const void*)lig,
                     pro_pos, lig_pos, pro_batch, lig_start, PtP,
                     pro, bout_pro, g_pro, b_pro, outp, NLr*DIM, NLr);
}

// Round 9
// 480.861 us; speedup vs baseline: 3.0495x; 1.2738x over previous
//
#include <hip/hip_runtime.h>

static constexpr int NLr = 2048;    // ligand rows
static constexpr int NPr = 16384;   // protein rows
static constexpr int DIM = 256;     // feature dim
static constexpr int NB  = 32;      // batch count

typedef unsigned short bf16_t;
using bf16x8 = __attribute__((ext_vector_type(8))) short;
using f32x4  = __attribute__((ext_vector_type(4))) float;

__device__ inline float bf2f(bf16_t u){
  union { unsigned int i; float f; } c; c.i = ((unsigned int)u) << 16; return c.f;
}
__device__ inline bf16_t f2bf(float f){
  union { float f; unsigned int i; } c; c.f = f;
  unsigned int x = c.i;
  return (bf16_t)((x + 0x7fffu + ((x >> 16) & 1u)) >> 16);  // RNE
}
template<int FMT>   // 1 = fp32, 0 = bf16
__device__ inline void ld4t(const void* p, size_t idx, float* o){
  if constexpr (FMT){
    float4 f = *reinterpret_cast<const float4*>((const float*)p + idx);
    o[0]=f.x; o[1]=f.y; o[2]=f.z; o[3]=f.w;
  } else {
    ushort4 u = *reinterpret_cast<const ushort4*>((const bf16_t*)p + idx);
    o[0]=bf2f(u.x); o[1]=bf2f(u.y); o[2]=bf2f(u.z); o[3]=bf2f(u.w);
  }
}
__device__ inline float wave_sum(float x){
  #pragma unroll
  for (int off = 32; off; off >>= 1) x += __shfl_xor(x, off, 64);
  return x;
}
__device__ inline bf16x8 ldfrag_bf16(const bf16_t* p){
  return *reinterpret_cast<const bf16x8*>(p);
}
__device__ inline bf16x8 ldfrag_f32(const float* p){
  float4 a = *reinterpret_cast<const float4*>(p);
  float4 b = *reinterpret_cast<const float4*>(p + 4);
  bf16x8 r;
  r[0]=(short)f2bf(a.x); r[1]=(short)f2bf(a.y); r[2]=(short)f2bf(a.z); r[3]=(short)f2bf(a.w);
  r[4]=(short)f2bf(b.x); r[5]=(short)f2bf(b.y); r[6]=(short)f2bf(b.z); r[7]=(short)f2bf(b.w);
  return r;
}
// fp32 -> (hi, lo) bf16 pair; hi+lo reconstructs v to ~2^-17 relative
__device__ inline void hilo8(const float* p, bf16x8& hi, bf16x8& lo){
  #pragma unroll
  for (int i = 0; i < 8; i++){
    float v = p[i];
    bf16_t h = f2bf(v);
    hi[i] = (short)h;
    lo[i] = (short)f2bf(v - bf2f(h));
  }
}

// ---- batch block boundaries ----
__global__ void bounds_kernel(const int* __restrict__ lb, const int* __restrict__ pb,
                              int* __restrict__ ls, int* __restrict__ ps){
  int t = threadIdx.x;
  if (t <= NB){
    int lo = 0, hi = NLr;
    while (lo < hi){ int mid = (lo + hi) >> 1; if (lb[mid] < t) lo = mid + 1; else hi = mid; }
    ls[t] = lo;
    lo = 0; hi = NPr;
    while (lo < hi){ int mid = (lo + hi) >> 1; if (pb[mid] < t) lo = mid + 1; else hi = mid; }
    ps[t] = lo;
  }
}

// ---- C[i,n] = sum_k A[k,i]*B[k,n]  (A^T B), 256x256, fp32 in, bf16 out ----
__global__ __launch_bounds__(256) void wprod_atb(
    const float* __restrict__ A, const float* __restrict__ B, bf16_t* __restrict__ C){
  __shared__ float As[16][68];
  __shared__ float Bs[16][68];
  const int t  = threadIdx.x;
  const int kk = t >> 4;
  const int c0 = (t & 15) << 2;
  const int tx = t & 15, ty = t >> 4;
  const int bm = blockIdx.x, bn = blockIdx.y;
  float acc[4][4] = {};
  for (int kt = 0; kt < DIM; kt += 16){
    float av[4], bv[4];
    ld4t<1>(A, (size_t)(kt+kk)*DIM + bm*64 + c0, av);
    ld4t<1>(B, (size_t)(kt+kk)*DIM + bn*64 + c0, bv);
    #pragma unroll
    for (int q = 0; q < 4; q++){ As[kk][c0+q]=av[q]; Bs[kk][c0+q]=bv[q]; }
    __syncthreads();
    #pragma unroll
    for (int k = 0; k < 16; k++){
      float a[4], b[4];
      #pragma unroll
      for (int i = 0; i < 4; i++) a[i] = As[k][ty*4+i];
      #pragma unroll
      for (int j = 0; j < 4; j++) b[j] = Bs[k][tx*4+j];
      #pragma unroll
      for (int i = 0; i < 4; i++)
        #pragma unroll
        for (int j = 0; j < 4; j++)
          acc[i][j] += a[i]*b[j];
    }
    __syncthreads();
  }
  #pragma unroll
  for (int i = 0; i < 4; i++){
    ushort4 o;
    o.x=f2bf(acc[i][0]); o.y=f2bf(acc[i][1]); o.z=f2bf(acc[i][2]); o.w=f2bf(acc[i][3]);
    *reinterpret_cast<ushort4*>(C + (size_t)(bm*64+ty*4+i)*DIM + bn*64 + tx*4) = o;
  }
}

// ---- C[i,n] = sum_k A[i,k]*B[k,n]  (A B), 256x256, both fp32, bf16 out ----
__global__ __launch_bounds__(256) void wprod_ab(
    const float* __restrict__ A, const float* __restrict__ B, bf16_t* __restrict__ C){
  __shared__ float As[64][17];
  __shared__ float Bs[16][68];
  const int t  = threadIdx.x;
  const int r  = t >> 2;
  const int k0 = (t & 3) << 2;
  const int kk = t >> 4;
  const int c0 = (t & 15) << 2;
  const int tx = t & 15, ty = t >> 4;
  const int bm = blockIdx.x, bn = blockIdx.y;
  float acc[4][4] = {};
  for (int kt = 0; kt < DIM; kt += 16){
    float av[4], bv[4];
    ld4t<1>(A, (size_t)(bm*64+r)*DIM + kt + k0, av);
    ld4t<1>(B, (size_t)(kt+kk)*DIM + bn*64 + c0, bv);
    #pragma unroll
    for (int q = 0; q < 4; q++){ As[r][k0+q]=av[q]; Bs[kk][c0+q]=bv[q]; }
    __syncthreads();
    #pragma unroll
    for (int k = 0; k < 16; k++){
      float a[4], b[4];
      #pragma unroll
      for (int i = 0; i < 4; i++) a[i] = As[ty*4+i][k];
      #pragma unroll
      for (int j = 0; j < 4; j++) b[j] = Bs[k][tx*4+j];
      #pragma unroll
      for (int i = 0; i < 4; i++)
        #pragma unroll
        for (int j = 0; j < 4; j++)
          acc[i][j] += a[i]*b[j];
    }
    __syncthreads();
  }
  #pragma unroll
  for (int i = 0; i < 4; i++){
    ushort4 o;
    o.x=f2bf(acc[i][0]); o.y=f2bf(acc[i][1]); o.z=f2bf(acc[i][2]); o.w=f2bf(acc[i][3]);
    *reinterpret_cast<ushort4*>(C + (size_t)(bm*64+ty*4+i)*DIM + bn*64 + tx*4) = o;
  }
}

// ---- C[i,n] = sum_k A[i,k]*B[k,n]; A fp32 [Mx256], B bf16 ws; C bf16 ----
__global__ __launch_bounds__(256) void gemm_ab(
    const float* __restrict__ A, const bf16_t* __restrict__ B, bf16_t* __restrict__ C){
  __shared__ float As[64][17];
  __shared__ float Bs[16][68];
  const int t  = threadIdx.x;
  const int r  = t >> 2;
  const int k0 = (t & 3) << 2;
  const int kk = t >> 4;
  const int c0 = (t & 15) << 2;
  const int tx = t & 15, ty = t >> 4;
  const int bm = blockIdx.x, bn = blockIdx.y;
  float acc[4][4] = {};
  for (int kt = 0; kt < DIM; kt += 16){
    float av[4], bv[4];
    ld4t<1>(A, (size_t)(bm*64+r)*DIM + kt + k0, av);
    ld4t<0>(B, (size_t)(kt+kk)*DIM + bn*64 + c0, bv);
    #pragma unroll
    for (int q = 0; q < 4; q++){ As[r][k0+q]=av[q]; Bs[kk][c0+q]=bv[q]; }
    __syncthreads();
    #pragma unroll
    for (int k = 0; k < 16; k++){
      float a[4], b[4];
      #pragma unroll
      for (int i = 0; i < 4; i++) a[i] = As[ty*4+i][k];
      #pragma unroll
      for (int j = 0; j < 4; j++) b[j] = Bs[k][tx*4+j];
      #pragma unroll
      for (int i = 0; i < 4; i++)
        #pragma unroll
        for (int j = 0; j < 4; j++)
          acc[i][j] += a[i]*b[j];
    }
    __syncthreads();
  }
  #pragma unroll
  for (int i = 0; i < 4; i++){
    ushort4 o;
    o.x=f2bf(acc[i][0]); o.y=f2bf(acc[i][1]); o.z=f2bf(acc[i][2]); o.w=f2bf(acc[i][3]);
    *reinterpret_cast<ushort4*>(C + (size_t)(bm*64+ty*4+i)*DIM + bn*64 + tx*4) = o;
  }
}

// ---- transpose + bf16 cast: A [R][256] fp32 -> At [256][CS] bf16 ----
__global__ __launch_bounds__(256) void transpose_cast(
    const float* __restrict__ A, bf16_t* __restrict__ At, int R, int CS){
  __shared__ float tile[64][65];
  const int t = threadIdx.x;
  const int r0 = blockIdx.x * 64, d0 = blockIdx.y * 64;
  #pragma unroll
  for (int i = 0; i < 4; i++){
    int r = (t >> 4) + i*16, c = (t & 15) << 2;
    float4 v = *reinterpret_cast<const float4*>(A + (size_t)(r0 + r)*DIM + d0 + c);
    tile[r][c+0]=v.x; tile[r][c+1]=v.y; tile[r][c+2]=v.z; tile[r][c+3]=v.w;
  }
  __syncthreads();
  #pragma unroll
  for (int i = 0; i < 4; i++){
    int dl = (t >> 4) + i*16, k = (t & 15) << 2;
    ushort4 o;
    o.x = f2bf(tile[k+0][dl]); o.y = f2bf(tile[k+1][dl]);
    o.z = f2bf(tile[k+2][dl]); o.w = f2bf(tile[k+3][dl]);
    *reinterpret_cast<ushort4*>(At + (size_t)(d0 + dl)*CS + r0 + k) = o;
  }
}

// ---- zero the 32 pad columns of At [256][CS], pad at [R, R+32) ----
__global__ void pad_zero(bf16_t* __restrict__ At, int R, int CS){
  int idx = blockIdx.x * 256 + threadIdx.x;   // grid 32 -> 8192 = 256*32
  int d = idx >> 5, k = idx & 31;
  At[(size_t)d*CS + R + k] = 0;
}

// ==== MFMA fused attention ====
// 16-row Q tile per (block if KSPLIT==2, wave if KSPLIT==1). Block = 128 thr.
// QF==1 uses hi/lo split Q frags (fp32-accurate scores). ctx kept fp32 in LDS;
// epilogue builds hi/lo A-frags on the fly: Y = ctx_hi*M + ctx_lo*M.
template<int QF, int KF, int KSPLIT>
__global__ __launch_bounds__(128) void attn_mfma(
    const void* __restrict__ Qp, const void* __restrict__ Kp,
    const bf16_t* __restrict__ Vt, int vstride,
    const float* __restrict__ posA, const float* __restrict__ posB,
    const int* __restrict__ batchA, const int* __restrict__ startB,
    const bf16_t* __restrict__ PtT,
    const float* __restrict__ X, const float* __restrict__ bo,
    const float* __restrict__ g, const float* __restrict__ bb,
    float* __restrict__ out, int out_off, int NK){
  // LDS plan (52 KB total):
  //  KSPLIT==2: [0,32768) O-partials (merge), later Y [16][260];
  //             [32768, +16640) ctx fp32 [16][260]
  //  KSPLIT==1: [0, 33280) ctx fp32 [2][16][260]; Y written in-place over ctx
  __shared__ char   ldsraw[49408];
  __shared__ bf16_t Pbuf[2][16][40];
  __shared__ float  mlb[2][2][16];
  float* Ob   = (float*)ldsraw;
  float* ctxf = (KSPLIT == 2) ? (float*)(ldsraw + 32768) : (float*)ldsraw;

  const int t = threadIdx.x, wl = t >> 6, lane = t & 63;
  const int qrow = lane & 15, q4 = lane >> 4;
  const int row0 = (KSPLIT == 2) ? blockIdx.x * 16 : (blockIdx.x * 2 + wl) * 16;

  const int rb = batchA[row0 + qrow];
  const int j0 = startB[rb], j1 = startB[rb + 1];
  const float ax = posA[(size_t)(row0+qrow)*3+0];
  const float ay = posA[(size_t)(row0+qrow)*3+1];
  const float az = posA[(size_t)(row0+qrow)*3+2];
  const int kmin = startB[batchA[row0]];
  const int kmax = startB[batchA[row0 + 15] + 1];
  const int base = kmin & ~31;

  // Q fragments (hi/lo when fp32 source)
  bf16x8 qf[8], ql[8];
  #pragma unroll
  for (int s = 0; s < 8; s++){
    if constexpr (QF == 0){
      qf[s] = ldfrag_bf16((const bf16_t*)Qp + (size_t)(row0+qrow)*DIM + s*32 + q4*8);
    } else {
      hilo8((const float*)Qp + (size_t)(row0+qrow)*DIM + s*32 + q4*8, qf[s], ql[s]);
    }
  }

  f32x4 O[16];
  #pragma unroll
  for (int i = 0; i < 16; i++) O[i] = (f32x4){0.f,0.f,0.f,0.f};
  float m_ = -3.0e38f, l_ = 0.f;

  const int cstep = (KSPLIT == 2) ? 64 : 32;
  for (int c0 = base + ((KSPLIT == 2) ? wl*32 : 0); c0 < kmax; c0 += cstep){
    // ---- score: S^T = K * Q^T (two 16-key halves) ----
    f32x4 a0 = (f32x4){0.f,0.f,0.f,0.f}, a1 = a0;
    const int k0c = min(c0 + qrow,      NK-1);
    const int k1c = min(c0 + 16 + qrow, NK-1);
    #pragma unroll
    for (int s = 0; s < 8; s++){
      bf16x8 ka, kb;
      if constexpr (KF == 0){
        ka = ldfrag_bf16((const bf16_t*)Kp + (size_t)k0c*DIM + s*32 + q4*8);
        kb = ldfrag_bf16((const bf16_t*)Kp + (size_t)k1c*DIM + s*32 + q4*8);
      } else {
        ka = ldfrag_f32((const float*)Kp + (size_t)k0c*DIM + s*32 + q4*8);
        kb = ldfrag_f32((const float*)Kp + (size_t)k1c*DIM + s*32 + q4*8);
      }
      a0 = __builtin_amdgcn_mfma_f32_16x16x32_bf16(ka, qf[s], a0, 0, 0, 0);
      a1 = __builtin_amdgcn_mfma_f32_16x16x32_bf16(kb, qf[s], a1, 0, 0, 0);
      if constexpr (QF == 1){
        a0 = __builtin_amdgcn_mfma_f32_16x16x32_bf16(ka, ql[s], a0, 0, 0, 0);
        a1 = __builtin_amdgcn_mfma_f32_16x16x32_bf16(kb, ql[s], a1, 0, 0, 0);
      }
    }
    // ---- bias + mask + online softmax (stats per qrow = lane&15) ----
    float sc[2][4]; bool vm[2][4];
    float cm = -3.0e38f;
    #pragma unroll
    for (int h = 0; h < 2; h++){
      #pragma unroll
      for (int r = 0; r < 4; r++){
        int key = c0 + h*16 + q4*4 + r;
        bool vld = (key >= j0) && (key < j1);
        int kc = min(key, NK-1);
        float bx = posB[(size_t)kc*3+0], by = posB[(size_t)kc*3+1], bz = posB[(size_t)kc*3+2];
        float dx = ax-bx, dy = ay-by, dz = az-bz;
        float dist = sqrtf(fmaxf(dx*dx + dy*dy + dz*dz, 1e-12f));
        float sv = (h ? a1[r] : a0[r]) * 0.0625f + __expf(-0.1f*dist);
        sc[h][r] = vld ? sv : -3.0e38f;
        vm[h][r] = vld;
        cm = fmaxf(cm, sc[h][r]);
      }
    }
    cm = fmaxf(cm, __shfl_xor(cm, 16));
    cm = fmaxf(cm, __shfl_xor(cm, 32));
    float mn = fmaxf(m_, cm);
    float aa = __expf(m_ - mn);
    float p[2][4]; float ps = 0.f;
    #pragma unroll
    for (int h = 0; h < 2; h++)
      #pragma unroll
      for (int r = 0; r < 4; r++){
        p[h][r] = vm[h][r] ? __expf(sc[h][r] - mn) : 0.f;
        ps += p[h][r];
      }
    ps += __shfl_xor(ps, 16);
    ps += __shfl_xor(ps, 32);
    l_ = l_*aa + ps;
    m_ = mn;
    // ---- P (C-layout) -> Pbuf[qrow][key] (A-frag layout) ----
    ushort4 w0, w1;
    w0.x=f2bf(p[0][0]); w0.y=f2bf(p[0][1]); w0.z=f2bf(p[0][2]); w0.w=f2bf(p[0][3]);
    w1.x=f2bf(p[1][0]); w1.y=f2bf(p[1][1]); w1.z=f2bf(p[1][2]); w1.w=f2bf(p[1][3]);
    *reinterpret_cast<ushort4*>(&Pbuf[wl][qrow][q4*4])      = w0;
    *reinterpret_cast<ushort4*>(&Pbuf[wl][qrow][16 + q4*4]) = w1;
    float af0 = __shfl(aa, q4*4+0), af1 = __shfl(aa, q4*4+1);
    float af2 = __shfl(aa, q4*4+2), af3 = __shfl(aa, q4*4+3);
    #pragma unroll
    for (int i = 0; i < 16; i++){
      O[i][0]*=af0; O[i][1]*=af1; O[i][2]*=af2; O[i][3]*=af3;
    }
    bf16x8 pa = *reinterpret_cast<const bf16x8*>(&Pbuf[wl][qrow][q4*8]);
    // ---- PV: O += P * V ----
    #pragma unroll
    for (int i = 0; i < 16; i++){
      const bf16_t* vp = Vt + (size_t)(i*16 + qrow)*vstride + c0 + q4*8;
      bf16x8 vb = *reinterpret_cast<const bf16x8*>(vp);
      O[i] = __builtin_amdgcn_mfma_f32_16x16x32_bf16(pa, vb, O[i], 0, 0, 0);
    }
  }

  if constexpr (KSPLIT == 2){
    if (lane < 16){ mlb[wl][0][lane] = m_; mlb[wl][1][lane] = l_; }
    #pragma unroll
    for (int i = 0; i < 16; i++)
      #pragma unroll
      for (int r = 0; r < 4; r++)
        Ob[wl*4096 + (q4*4+r)*256 + i*16 + qrow] = O[i][r];
    __syncthreads();
    for (int e = t; e < 4096; e += 128){
      int row = e >> 8, d = e & 255;
      float m0 = mlb[0][0][row], l0 = mlb[0][1][row];
      float m1 = mlb[1][0][row], l1 = mlb[1][1][row];
      float mg = fmaxf(m0, m1);
      float f0 = __expf(m0 - mg), f1 = __expf(m1 - mg);
      float den = l0*f0 + l1*f1;
      float v = Ob[row*256 + d]*f0 + Ob[4096 + row*256 + d]*f1;
      ctxf[row*260 + d] = (den > 0.f) ? v/den : 0.f;   // fp32, never rounded
    }
    __syncthreads();
  } else {
    float lr0 = __shfl(l_, q4*4+0), lr1 = __shfl(l_, q4*4+1);
    float lr2 = __shfl(l_, q4*4+2), lr3 = __shfl(l_, q4*4+3);
    float i0 = lr0>0.f?1.f/lr0:0.f, i1 = lr1>0.f?1.f/lr1:0.f;
    float i2 = lr2>0.f?1.f/lr2:0.f, i3 = lr3>0.f?1.f/lr3:0.f;
    float* cw = ctxf + wl*4160;   // [16][260]
    #pragma unroll
    for (int i = 0; i < 16; i++){
      cw[(q4*4+0)*260 + i*16+qrow] = O[i][0]*i0;
      cw[(q4*4+1)*260 + i*16+qrow] = O[i][1]*i1;
      cw[(q4*4+2)*260 + i*16+qrow] = O[i][2]*i2;
      cw[(q4*4+3)*260 + i*16+qrow] = O[i][3]*i3;
    }
  }

  // ---- epilogue: Y = ctx_hi*M + ctx_lo*M via MFMA (B-frags from PtT = M^T) ----
  const float* cw = (KSPLIT == 2) ? ctxf : ctxf + wl*4160;
  const int tbase = (KSPLIT == 2) ? wl*8 : 0;
  const int TN    = (KSPLIT == 2) ? 8 : 16;
  f32x4 Y[16];
  #pragma unroll
  for (int i = 0; i < 16; i++) Y[i] = (f32x4){0.f,0.f,0.f,0.f};
  #pragma unroll
  for (int s = 0; s < 8; s++){
    bf16x8 ca, cl;
    hilo8(cw + qrow*260 + s*32 + q4*8, ca, cl);
    for (int tt = 0; tt < TN; tt++){
      const bf16_t* pb = PtT + (size_t)((tbase+tt)*16 + qrow)*DIM + s*32 + q4*8;
      bf16x8 mb = *reinterpret_cast<const bf16x8*>(pb);
      Y[tt] = __builtin_amdgcn_mfma_f32_16x16x32_bf16(ca, mb, Y[tt], 0, 0, 0);
      Y[tt] = __builtin_amdgcn_mfma_f32_16x16x32_bf16(cl, mb, Y[tt], 0, 0, 0);
    }
  }
  // Y buffer: KSPLIT==2 -> Ob region (merge done); KSPLIT==1 -> in-place over ctx
  float* YB = (KSPLIT == 2) ? Ob : (float*)(ctxf + wl*4160);
  for (int tt = 0; tt < TN; tt++){
    #pragma unroll
    for (int r = 0; r < 4; r++)
      YB[(q4*4+r)*260 + (tbase+tt)*16 + qrow] = Y[tt][r];
  }
  if (KSPLIT == 2) __syncthreads();

  // ---- residual + LN + store (fp32 out) ----
  const int rbase = (KSPLIT == 2) ? wl*8 : 0;
  const int RN    = (KSPLIT == 2) ? 8 : 16;
  for (int i = 0; i < RN; i++){
    int r = rbase + i, grow = row0 + r;
    float4 yv = *reinterpret_cast<const float4*>(&YB[r*260 + 4*lane]);
    float4 xv = *reinterpret_cast<const float4*>(X  + (size_t)grow*DIM + 4*lane);
    float4 bv = *reinterpret_cast<const float4*>(bo + 4*lane);
    float4 gv = *reinterpret_cast<const float4*>(g  + 4*lane);
    float4 b2 = *reinterpret_cast<const float4*>(bb + 4*lane);
    float v0 = xv.x + yv.x + bv.x, v1 = xv.y + yv.y + bv.y;
    float v2 = xv.z + yv.z + bv.z, v3 = xv.w + yv.w + bv.w;
    float sum = wave_sum(v0+v1+v2+v3);
    float ssq = wave_sum(v0*v0+v1*v1+v2*v2+v3*v3);
    float mu  = sum * (1.0f/DIM);
    float var = ssq * (1.0f/DIM) - mu*mu;
    float rr  = rsqrtf(fmaxf(var, 0.f) + 1e-5f);
    float4 o;
    o.x = (v0-mu)*rr*gv.x + b2.x;
    o.y = (v1-mu)*rr*gv.y + b2.y;
    o.z = (v2-mu)*rr*gv.z + b2.z;
    o.w = (v3-mu)*rr*gv.w + b2.w;
    *reinterpret_cast<float4*>(out + (size_t)out_off + (size_t)grow*DIM + 4*lane) = o;
  }
}

extern "C" void kernel_launch(void* const* d_in, const int* in_sizes, int n_in,
                              void* d_out, int out_size, void* d_ws, size_t ws_size,
                              hipStream_t stream){
  const float* lig      = (const float*)d_in[0];
  const float* pro      = (const float*)d_in[1];
  const float* lig_pos  = (const float*)d_in[2];
  const float* pro_pos  = (const float*)d_in[3];
  const int*   lig_batch= (const int*)d_in[4];
  const int*   pro_batch= (const int*)d_in[5];
  const float* Wq_lig   = (const float*)d_in[6];
  const float* Wk_pro   = (const float*)d_in[7];
  const float* Wv_pro   = (const float*)d_in[8];
  const float* Wq_pro   = (const float*)d_in[9];
  const float* Wk_lig   = (const float*)d_in[10];
  const float* Wv_lig   = (const float*)d_in[11];
  const float* Wout_lig = (const float*)d_in[12];
  const float* bout_lig = (const float*)d_in[13];
  const float* Wout_pro = (const float*)d_in[14];
  const float* bout_pro = (const float*)d_in[15];
  const float* g_lig    = (const float*)d_in[16];
  const float* b_lig    = (const float*)d_in[17];
  const float* g_pro    = (const float*)d_in[18];
  const float* b_pro    = (const float*)d_in[19];

  int* ib        = (int*)d_ws;
  int* lig_start = ib + 16;
  int* pro_start = ib + 56;
  bf16_t* wsb  = ((bf16_t*)d_ws) + 256;
  bf16_t* A1   = wsb;                         // Wq_lig^T Wk_pro
  bf16_t* B2   = A1   + DIM*DIM;              // Wk_lig^T Wq_pro
  bf16_t* PtTL = B2   + DIM*DIM;              // Wout_lig @ Wv_pro  (= M_lig^T)
  bf16_t* PtTP = PtTL + DIM*DIM;              // Wout_pro @ Wv_lig  (= M_pro^T)
  bf16_t* G    = PtTP + DIM*DIM;              // lig @ B2  [2048][256]
  bf16_t* T_lig= G    + (size_t)NLr*DIM;      // lig @ A1; later overlaid by ligT

  float* outp = (float*)d_out;
  // proT [256][16416] bf16 in the tail of d_out (consumed by lig attn first)
  bf16_t* proT = (bf16_t*)(outp + 2617344);
  bf16_t* ligT = T_lig;                       // [256][2080], overlays T_lig after lig attn

  hipLaunchKernelGGL(bounds_kernel, dim3(1), dim3(64), 0, stream,
                     lig_batch, pro_batch, lig_start, pro_start);

  dim3 gw(4,4), gl(NLr/64, 4);
  hipLaunchKernelGGL(wprod_atb, gw, dim3(256), 0, stream, Wq_lig, Wk_pro, A1);
  hipLaunchKernelGGL(wprod_atb, gw, dim3(256), 0, stream, Wk_lig, Wq_pro, B2);
  hipLaunchKernelGGL(wprod_ab,  gw, dim3(256), 0, stream, Wout_lig, Wv_pro, PtTL);
  hipLaunchKernelGGL(wprod_ab,  gw, dim3(256), 0, stream, Wout_pro, Wv_lig, PtTP);
  hipLaunchKernelGGL(gemm_ab, gl, dim3(256), 0, stream, lig, A1, T_lig);
  hipLaunchKernelGGL(gemm_ab, gl, dim3(256), 0, stream, lig, B2, G);

  hipLaunchKernelGGL(transpose_cast, dim3(NPr/64, 4), dim3(256), 0, stream,
                     pro, proT, NPr, NPr+32);
  hipLaunchKernelGGL(pad_zero, dim3(32), dim3(256), 0, stream, proT, NPr, NPr+32);

  // ligand <- protein: Q=T_lig(bf16), K=pro(fp32), V=proT; 2-way key-split
  hipLaunchKernelGGL((attn_mfma<0,1,2>), dim3(NLr/16), dim3(128), 0, stream,
                     (const void*)T_lig, (const void*)pro, proT, NPr+32,
                     lig_pos, pro_pos, lig_batch, pro_start, PtTL,
                     lig, bout_lig, g_lig, b_lig, outp, 0, NPr);

  hipLaunchKernelGGL(transpose_cast, dim3(NLr/64, 4), dim3(256), 0, stream,
                     lig, ligT, NLr, NLr+32);
  hipLaunchKernelGGL(pad_zero, dim3(32), dim3(256), 0, stream, ligT, NLr, NLr+32);

  // protein <- ligand: Q=pro(fp32, hi/lo split), K=G(bf16), V=ligT; 1 tile/wave
  hipLaunchKernelGGL((attn_mfma<1,0,1>), dim3(NPr/32), dim3(128), 0, stream,
                     (const void*)pro, (const void*)G, ligT, NLr+32,
                     pro_pos, lig_pos, pro_batch, lig_start, PtTP,
                     pro, bout_pro, g_pro, b_pro, outp, NLr*DIM, NLr);
}

// Round 10
// 338.771 us; speedup vs baseline: 4.3286x; 1.4194x over previous
//
#include <hip/hip_runtime.h>

static constexpr int NLr = 2048;    // ligand rows
static constexpr int NPr = 16384;   // protein rows
static constexpr int DIM = 256;     // feature dim
static constexpr int NB  = 32;      // batch count

typedef unsigned short bf16_t;
using bf16x8 = __attribute__((ext_vector_type(8))) short;
using f32x4  = __attribute__((ext_vector_type(4))) float;

__device__ inline float bf2f(bf16_t u){
  union { unsigned int i; float f; } c; c.i = ((unsigned int)u) << 16; return c.f;
}
__device__ inline bf16_t f2bf(float f){
  union { float f; unsigned int i; } c; c.f = f;
  unsigned int x = c.i;
  return (bf16_t)((x + 0x7fffu + ((x >> 16) & 1u)) >> 16);  // RNE
}
template<int FMT>   // 1 = fp32, 0 = bf16
__device__ inline void ld4t(const void* p, size_t idx, float* o){
  if constexpr (FMT){
    float4 f = *reinterpret_cast<const float4*>((const float*)p + idx);
    o[0]=f.x; o[1]=f.y; o[2]=f.z; o[3]=f.w;
  } else {
    ushort4 u = *reinterpret_cast<const ushort4*>((const bf16_t*)p + idx);
    o[0]=bf2f(u.x); o[1]=bf2f(u.y); o[2]=bf2f(u.z); o[3]=bf2f(u.w);
  }
}
__device__ inline float wave_sum(float x){
  #pragma unroll
  for (int off = 32; off; off >>= 1) x += __shfl_xor(x, off, 64);
  return x;
}
// fp32 -> (hi, lo) bf16 pair
__device__ inline void hilo8(const float* p, bf16x8& hi, bf16x8& lo){
  #pragma unroll
  for (int i = 0; i < 8; i++){
    float v = p[i];
    bf16_t h = f2bf(v);
    hi[i] = (short)h;
    lo[i] = (short)f2bf(v - bf2f(h));
  }
}

// ---- batch block boundaries ----
__global__ void bounds_kernel(const int* __restrict__ lb, const int* __restrict__ pb,
                              int* __restrict__ ls, int* __restrict__ ps){
  int t = threadIdx.x;
  if (t <= NB){
    int lo = 0, hi = NLr;
    while (lo < hi){ int mid = (lo + hi) >> 1; if (lb[mid] < t) lo = mid + 1; else hi = mid; }
    ls[t] = lo;
    lo = 0; hi = NPr;
    while (lo < hi){ int mid = (lo + hi) >> 1; if (pb[mid] < t) lo = mid + 1; else hi = mid; }
    ps[t] = lo;
  }
}

// ---- fp32 -> bf16 row-major cast (n multiple of 4) ----
__global__ __launch_bounds__(256) void cast_bf16(
    const float* __restrict__ src, bf16_t* __restrict__ dst, int n){
  int i = (blockIdx.x * 256 + threadIdx.x) * 4;
  if (i < n){
    float4 v = *reinterpret_cast<const float4*>(src + i);
    ushort4 o;
    o.x = f2bf(v.x); o.y = f2bf(v.y); o.z = f2bf(v.z); o.w = f2bf(v.w);
    *reinterpret_cast<ushort4*>(dst + i) = o;
  }
}

// ---- C[i,n] = sum_k A[k,i]*B[k,n]  (A^T B), 256x256, fp32 in, bf16 out ----
__global__ __launch_bounds__(256) void wprod_atb(
    const float* __restrict__ A, const float* __restrict__ B, bf16_t* __restrict__ C){
  __shared__ float As[16][68];
  __shared__ float Bs[16][68];
  const int t  = threadIdx.x;
  const int kk = t >> 4;
  const int c0 = (t & 15) << 2;
  const int tx = t & 15, ty = t >> 4;
  const int bm = blockIdx.x, bn = blockIdx.y;
  float acc[4][4] = {};
  for (int kt = 0; kt < DIM; kt += 16){
    float av[4], bv[4];
    ld4t<1>(A, (size_t)(kt+kk)*DIM + bm*64 + c0, av);
    ld4t<1>(B, (size_t)(kt+kk)*DIM + bn*64 + c0, bv);
    #pragma unroll
    for (int q = 0; q < 4; q++){ As[kk][c0+q]=av[q]; Bs[kk][c0+q]=bv[q]; }
    __syncthreads();
    #pragma unroll
    for (int k = 0; k < 16; k++){
      float a[4], b[4];
      #pragma unroll
      for (int i = 0; i < 4; i++) a[i] = As[k][ty*4+i];
      #pragma unroll
      for (int j = 0; j < 4; j++) b[j] = Bs[k][tx*4+j];
      #pragma unroll
      for (int i = 0; i < 4; i++)
        #pragma unroll
        for (int j = 0; j < 4; j++)
          acc[i][j] += a[i]*b[j];
    }
    __syncthreads();
  }
  #pragma unroll
  for (int i = 0; i < 4; i++){
    ushort4 o;
    o.x=f2bf(acc[i][0]); o.y=f2bf(acc[i][1]); o.z=f2bf(acc[i][2]); o.w=f2bf(acc[i][3]);
    *reinterpret_cast<ushort4*>(C + (size_t)(bm*64+ty*4+i)*DIM + bn*64 + tx*4) = o;
  }
}

// ---- C[i,n] = sum_k A[i,k]*B[k,n]  (A B), 256x256, both fp32, bf16 out ----
__global__ __launch_bounds__(256) void wprod_ab(
    const float* __restrict__ A, const float* __restrict__ B, bf16_t* __restrict__ C){
  __shared__ float As[64][17];
  __shared__ float Bs[16][68];
  const int t  = threadIdx.x;
  const int r  = t >> 2;
  const int k0 = (t & 3) << 2;
  const int kk = t >> 4;
  const int c0 = (t & 15) << 2;
  const int tx = t & 15, ty = t >> 4;
  const int bm = blockIdx.x, bn = blockIdx.y;
  float acc[4][4] = {};
  for (int kt = 0; kt < DIM; kt += 16){
    float av[4], bv[4];
    ld4t<1>(A, (size_t)(bm*64+r)*DIM + kt + k0, av);
    ld4t<1>(B, (size_t)(kt+kk)*DIM + bn*64 + c0, bv);
    #pragma unroll
    for (int q = 0; q < 4; q++){ As[r][k0+q]=av[q]; Bs[kk][c0+q]=bv[q]; }
    __syncthreads();
    #pragma unroll
    for (int k = 0; k < 16; k++){
      float a[4], b[4];
      #pragma unroll
      for (int i = 0; i < 4; i++) a[i] = As[ty*4+i][k];
      #pragma unroll
      for (int j = 0; j < 4; j++) b[j] = Bs[k][tx*4+j];
      #pragma unroll
      for (int i = 0; i < 4; i++)
        #pragma unroll
        for (int j = 0; j < 4; j++)
          acc[i][j] += a[i]*b[j];
    }
    __syncthreads();
  }
  #pragma unroll
  for (int i = 0; i < 4; i++){
    ushort4 o;
    o.x=f2bf(acc[i][0]); o.y=f2bf(acc[i][1]); o.z=f2bf(acc[i][2]); o.w=f2bf(acc[i][3]);
    *reinterpret_cast<ushort4*>(C + (size_t)(bm*64+ty*4+i)*DIM + bn*64 + tx*4) = o;
  }
}

// ---- C[i,n] = sum_k A[i,k]*B[k,n]; A fp32 [Mx256], B bf16 ws; C bf16 ----
__global__ __launch_bounds__(256) void gemm_ab(
    const float* __restrict__ A, const bf16_t* __restrict__ B, bf16_t* __restrict__ C){
  __shared__ float As[64][17];
  __shared__ float Bs[16][68];
  const int t  = threadIdx.x;
  const int r  = t >> 2;
  const int k0 = (t & 3) << 2;
  const int kk = t >> 4;
  const int c0 = (t & 15) << 2;
  const int tx = t & 15, ty = t >> 4;
  const int bm = blockIdx.x, bn = blockIdx.y;
  float acc[4][4] = {};
  for (int kt = 0; kt < DIM; kt += 16){
    float av[4], bv[4];
    ld4t<1>(A, (size_t)(bm*64+r)*DIM + kt + k0, av);
    ld4t<0>(B, (size_t)(kt+kk)*DIM + bn*64 + c0, bv);
    #pragma unroll
    for (int q = 0; q < 4; q++){ As[r][k0+q]=av[q]; Bs[kk][c0+q]=bv[q]; }
    __syncthreads();
    #pragma unroll
    for (int k = 0; k < 16; k++){
      float a[4], b[4];
      #pragma unroll
      for (int i = 0; i < 4; i++) a[i] = As[ty*4+i][k];
      #pragma unroll
      for (int j = 0; j < 4; j++) b[j] = Bs[k][tx*4+j];
      #pragma unroll
      for (int i = 0; i < 4; i++)
        #pragma unroll
        for (int j = 0; j < 4; j++)
          acc[i][j] += a[i]*b[j];
    }
    __syncthreads();
  }
  #pragma unroll
  for (int i = 0; i < 4; i++){
    ushort4 o;
    o.x=f2bf(acc[i][0]); o.y=f2bf(acc[i][1]); o.z=f2bf(acc[i][2]); o.w=f2bf(acc[i][3]);
    *reinterpret_cast<ushort4*>(C + (size_t)(bm*64+ty*4+i)*DIM + bn*64 + tx*4) = o;
  }
}

// ==== MFMA fused attention v2: LDS-staged V, row-major bf16 K direct ====
// KSPLIT==2 (lig): one 16-row tile per block, 2 waves split keys, LDS merge.
// KSPLIT==1 (pro): two 16-row tiles per block (one per wave), shared staging.
// QF==1: fp32 Q with hi/lo split. Kbf/Vbf: row-major bf16 [NK][256].
template<int QF, int KSPLIT>
__global__ __launch_bounds__(128) void attn2(
    const void* __restrict__ Qp, const bf16_t* __restrict__ Kbf,
    const bf16_t* __restrict__ Vbf,
    const float* __restrict__ posA, const float* __restrict__ posB,
    const int* __restrict__ batchA, const int* __restrict__ startB,
    const bf16_t* __restrict__ PtT,
    const float* __restrict__ X, const float* __restrict__ bo,
    const float* __restrict__ g, const float* __restrict__ bb,
    float* __restrict__ out, int out_off, int NK){
  constexpr int SK = (KSPLIT == 2) ? 64 : 32;   // staged keys per round
  constexpr int VW = (KSPLIT == 2) ? 72 : 40;   // Vlds row stride (16B-aligned)
  // raw region: Vlds [256][VW] bf16 during loop; Ob partials / Y buf after (KSPLIT2)
  __shared__ char  ldsraw[(KSPLIT == 2) ? 36864 : 20480];
  __shared__ float ctxl[(KSPLIT == 2 ? 1 : 2) * 16 * 260];
  __shared__ bf16_t Pbuf[2][16][40];
  __shared__ float  mlb[2][2][16];
  bf16_t* Vlds = (bf16_t*)ldsraw;
  float*  Ob   = (float*)ldsraw;

  const int t = threadIdx.x, wl = t >> 6, lane = t & 63;
  const int qrow = lane & 15, q4 = lane >> 4;
  const int row0b = blockIdx.x * ((KSPLIT == 2) ? 16 : 32);
  const int row0  = (KSPLIT == 2) ? row0b : row0b + wl*16;

  const int rb = batchA[row0 + qrow];
  const int j0 = startB[rb], j1 = startB[rb + 1];
  const float ax = posA[(size_t)(row0+qrow)*3+0];
  const float ay = posA[(size_t)(row0+qrow)*3+1];
  const float az = posA[(size_t)(row0+qrow)*3+2];
  const int kmin = startB[batchA[row0b]];
  const int kmax = startB[batchA[row0b + ((KSPLIT == 2) ? 15 : 31)] + 1];
  const int base = kmin & ~(SK - 1);

  // Q fragments
  bf16x8 qf[8], ql[8];
  #pragma unroll
  for (int s = 0; s < 8; s++){
    if constexpr (QF == 0){
      qf[s] = *reinterpret_cast<const bf16x8*>(
                (const bf16_t*)Qp + (size_t)(row0+qrow)*DIM + s*32 + q4*8);
    } else {
      hilo8((const float*)Qp + (size_t)(row0+qrow)*DIM + s*32 + q4*8, qf[s], ql[s]);
    }
  }

  f32x4 O[16];
  #pragma unroll
  for (int i = 0; i < 16; i++) O[i] = (f32x4){0.f,0.f,0.f,0.f};
  float m_ = -3.0e38f, l_ = 0.f;

  // staging thread mapping
  const int sk2 = t & (SK - 1);
  const int spp = t / SK;
  constexpr int DPT = 256 / (128 / SK);   // dims per staging thread
  const int sd0 = spp * DPT;

  for (int c = base; c < kmax; c += SK){
    __syncthreads();   // prev round's readers done before overwrite
    {
      int krow = min(c + sk2, NK - 1);
      const bf16_t* src = Vbf + (size_t)krow*DIM + sd0;
      for (int d = 0; d < DPT; d += 8){
        bf16x8 v = *reinterpret_cast<const bf16x8*>(src + d);
        #pragma unroll
        for (int jj = 0; jj < 8; jj++)
          Vlds[(sd0 + d + jj)*VW + sk2] = (bf16_t)v[jj];
      }
    }
    __syncthreads();

    const int kc0     = c + ((KSPLIT == 2) ? wl*32 : 0);
    const int colbase = (KSPLIT == 2) ? wl*32 : 0;
    // ---- score: S^T = K * Q^T, K A-frags direct from global bf16 (L2-warm) ----
    f32x4 a0 = (f32x4){0.f,0.f,0.f,0.f}, a1 = a0;
    const bf16_t* kr0 = Kbf + (size_t)min(kc0 + qrow,      NK-1)*DIM;
    const bf16_t* kr1 = Kbf + (size_t)min(kc0 + 16 + qrow, NK-1)*DIM;
    #pragma unroll
    for (int s = 0; s < 8; s++){
      bf16x8 ka = *reinterpret_cast<const bf16x8*>(kr0 + s*32 + q4*8);
      bf16x8 kb = *reinterpret_cast<const bf16x8*>(kr1 + s*32 + q4*8);
      a0 = __builtin_amdgcn_mfma_f32_16x16x32_bf16(ka, qf[s], a0, 0, 0, 0);
      a1 = __builtin_amdgcn_mfma_f32_16x16x32_bf16(kb, qf[s], a1, 0, 0, 0);
      if constexpr (QF == 1){
        a0 = __builtin_amdgcn_mfma_f32_16x16x32_bf16(ka, ql[s], a0, 0, 0, 0);
        a1 = __builtin_amdgcn_mfma_f32_16x16x32_bf16(kb, ql[s], a1, 0, 0, 0);
      }
    }
    // ---- bias + mask + online softmax (stats per qrow) ----
    float sc[2][4]; bool vm[2][4];
    float cm = -3.0e38f;
    #pragma unroll
    for (int h = 0; h < 2; h++){
      #pragma unroll
      for (int r = 0; r < 4; r++){
        int key = kc0 + h*16 + q4*4 + r;
        bool vld = (key >= j0) && (key < j1);
        int kc = min(key, NK-1);
        float bx = posB[(size_t)kc*3+0], by = posB[(size_t)kc*3+1], bz = posB[(size_t)kc*3+2];
        float dx = ax-bx, dy = ay-by, dz = az-bz;
        float dist = sqrtf(fmaxf(dx*dx + dy*dy + dz*dz, 1e-12f));
        float sv = (h ? a1[r] : a0[r]) * 0.0625f + __expf(-0.1f*dist);
        sc[h][r] = vld ? sv : -3.0e38f;
        vm[h][r] = vld;
        cm = fmaxf(cm, sc[h][r]);
      }
    }
    cm = fmaxf(cm, __shfl_xor(cm, 16));
    cm = fmaxf(cm, __shfl_xor(cm, 32));
    float mn = fmaxf(m_, cm);
    float aa = __expf(m_ - mn);
    float p[2][4]; float ps = 0.f;
    #pragma unroll
    for (int h = 0; h < 2; h++)
      #pragma unroll
      for (int r = 0; r < 4; r++){
        p[h][r] = vm[h][r] ? __expf(sc[h][r] - mn) : 0.f;
        ps += p[h][r];
      }
    ps += __shfl_xor(ps, 16);
    ps += __shfl_xor(ps, 32);
    l_ = l_*aa + ps;
    m_ = mn;
    // ---- P (C-layout) -> Pbuf (A-frag layout) ----
    ushort4 w0, w1;
    w0.x=f2bf(p[0][0]); w0.y=f2bf(p[0][1]); w0.z=f2bf(p[0][2]); w0.w=f2bf(p[0][3]);
    w1.x=f2bf(p[1][0]); w1.y=f2bf(p[1][1]); w1.z=f2bf(p[1][2]); w1.w=f2bf(p[1][3]);
    *reinterpret_cast<ushort4*>(&Pbuf[wl][qrow][q4*4])      = w0;
    *reinterpret_cast<ushort4*>(&Pbuf[wl][qrow][16 + q4*4]) = w1;
    float af0 = __shfl(aa, q4*4+0), af1 = __shfl(aa, q4*4+1);
    float af2 = __shfl(aa, q4*4+2), af3 = __shfl(aa, q4*4+3);
    #pragma unroll
    for (int i = 0; i < 16; i++){
      O[i][0]*=af0; O[i][1]*=af1; O[i][2]*=af2; O[i][3]*=af3;
    }
    bf16x8 pa = *reinterpret_cast<const bf16x8*>(&Pbuf[wl][qrow][q4*8]);
    // ---- PV: O += P * V, B-frags from LDS (b128, aligned) ----
    #pragma unroll
    for (int i = 0; i < 16; i++){
      const bf16_t* vp = Vlds + (size_t)(i*16 + qrow)*VW + colbase + q4*8;
      bf16x8 vb = *reinterpret_cast<const bf16x8*>(vp);
      O[i] = __builtin_amdgcn_mfma_f32_16x16x32_bf16(pa, vb, O[i], 0, 0, 0);
    }
  }

  if constexpr (KSPLIT == 2){
    __syncthreads();   // Vlds readers done; raw region becomes Ob
    if (lane < 16){ mlb[wl][0][lane] = m_; mlb[wl][1][lane] = l_; }
    #pragma unroll
    for (int i = 0; i < 16; i++)
      #pragma unroll
      for (int r = 0; r < 4; r++)
        Ob[wl*4096 + (q4*4+r)*256 + i*16 + qrow] = O[i][r];
    __syncthreads();
    for (int e = t; e < 4096; e += 128){
      int row = e >> 8, d = e & 255;
      float m0 = mlb[0][0][row], l0 = mlb[0][1][row];
      float m1 = mlb[1][0][row], l1 = mlb[1][1][row];
      float mg = fmaxf(m0, m1);
      float f0 = __expf(m0 - mg), f1 = __expf(m1 - mg);
      float den = l0*f0 + l1*f1;
      float v = Ob[row*256 + d]*f0 + Ob[4096 + row*256 + d]*f1;
      ctxl[row*260 + d] = (den > 0.f) ? v/den : 0.f;
    }
    __syncthreads();
  } else {
    float lr0 = __shfl(l_, q4*4+0), lr1 = __shfl(l_, q4*4+1);
    float lr2 = __shfl(l_, q4*4+2), lr3 = __shfl(l_, q4*4+3);
    float i0 = lr0>0.f?1.f/lr0:0.f, i1 = lr1>0.f?1.f/lr1:0.f;
    float i2 = lr2>0.f?1.f/lr2:0.f, i3 = lr3>0.f?1.f/lr3:0.f;
    float* cw = ctxl + wl*4160;
    #pragma unroll
    for (int i = 0; i < 16; i++){
      cw[(q4*4+0)*260 + i*16+qrow] = O[i][0]*i0;
      cw[(q4*4+1)*260 + i*16+qrow] = O[i][1]*i1;
      cw[(q4*4+2)*260 + i*16+qrow] = O[i][2]*i2;
      cw[(q4*4+3)*260 + i*16+qrow] = O[i][3]*i3;
    }
  }

  // ---- epilogue: Y = ctx_hi*M + ctx_lo*M (B-frags from PtT = M^T) ----
  const float* cw = (KSPLIT == 2) ? ctxl : ctxl + wl*4160;
  const int tbase = (KSPLIT == 2) ? wl*8 : 0;
  const int TN    = (KSPLIT == 2) ? 8 : 16;
  f32x4 Y[16];
  #pragma unroll
  for (int i = 0; i < 16; i++) Y[i] = (f32x4){0.f,0.f,0.f,0.f};
  #pragma unroll
  for (int s = 0; s < 8; s++){
    bf16x8 ca, cl;
    hilo8(cw + qrow*260 + s*32 + q4*8, ca, cl);
    for (int tt = 0; tt < TN; tt++){
      const bf16_t* pb = PtT + (size_t)((tbase+tt)*16 + qrow)*DIM + s*32 + q4*8;
      bf16x8 mb = *reinterpret_cast<const bf16x8*>(pb);
      Y[tt] = __builtin_amdgcn_mfma_f32_16x16x32_bf16(ca, mb, Y[tt], 0, 0, 0);
      Y[tt] = __builtin_amdgcn_mfma_f32_16x16x32_bf16(cl, mb, Y[tt], 0, 0, 0);
    }
  }
  float* YB = (KSPLIT == 2) ? Ob : (ctxl + wl*4160);
  for (int tt = 0; tt < TN; tt++){
    #pragma unroll
    for (int r = 0; r < 4; r++)
      YB[(q4*4+r)*260 + (tbase+tt)*16 + qrow] = Y[tt][r];
  }
  if (KSPLIT == 2) __syncthreads();

  // ---- residual + LN + store (fp32 out) ----
  const int rbase = (KSPLIT == 2) ? wl*8 : 0;
  const int RN    = (KSPLIT == 2) ? 8 : 16;
  for (int i = 0; i < RN; i++){
    int r = rbase + i, grow = row0 + r;
    float4 yv = *reinterpret_cast<const float4*>(&YB[r*260 + 4*lane]);
    float4 xv = *reinterpret_cast<const float4*>(X  + (size_t)grow*DIM + 4*lane);
    float4 bv = *reinterpret_cast<const float4*>(bo + 4*lane);
    float4 gv = *reinterpret_cast<const float4*>(g  + 4*lane);
    float4 b2 = *reinterpret_cast<const float4*>(bb + 4*lane);
    float v0 = xv.x + yv.x + bv.x, v1 = xv.y + yv.y + bv.y;
    float v2 = xv.z + yv.z + bv.z, v3 = xv.w + yv.w + bv.w;
    float sum = wave_sum(v0+v1+v2+v3);
    float ssq = wave_sum(v0*v0+v1*v1+v2*v2+v3*v3);
    float mu  = sum * (1.0f/DIM);
    float var = ssq * (1.0f/DIM) - mu*mu;
    float rr  = rsqrtf(fmaxf(var, 0.f) + 1e-5f);
    float4 o;
    o.x = (v0-mu)*rr*gv.x + b2.x;
    o.y = (v1-mu)*rr*gv.y + b2.y;
    o.z = (v2-mu)*rr*gv.z + b2.z;
    o.w = (v3-mu)*rr*gv.w + b2.w;
    *reinterpret_cast<float4*>(out + (size_t)out_off + (size_t)grow*DIM + 4*lane) = o;
  }
}

extern "C" void kernel_launch(void* const* d_in, const int* in_sizes, int n_in,
                              void* d_out, int out_size, void* d_ws, size_t ws_size,
                              hipStream_t stream){
  const float* lig      = (const float*)d_in[0];
  const float* pro      = (const float*)d_in[1];
  const float* lig_pos  = (const float*)d_in[2];
  const float* pro_pos  = (const float*)d_in[3];
  const int*   lig_batch= (const int*)d_in[4];
  const int*   pro_batch= (const int*)d_in[5];
  const float* Wq_lig   = (const float*)d_in[6];
  const float* Wk_pro   = (const float*)d_in[7];
  const float* Wv_pro   = (const float*)d_in[8];
  const float* Wq_pro   = (const float*)d_in[9];
  const float* Wk_lig   = (const float*)d_in[10];
  const float* Wv_lig   = (const float*)d_in[11];
  const float* Wout_lig = (const float*)d_in[12];
  const float* bout_lig = (const float*)d_in[13];
  const float* Wout_pro = (const float*)d_in[14];
  const float* bout_pro = (const float*)d_in[15];
  const float* g_lig    = (const float*)d_in[16];
  const float* b_lig    = (const float*)d_in[17];
  const float* g_pro    = (const float*)d_in[18];
  const float* b_pro    = (const float*)d_in[19];

  // ws (~3.67 MB): ints, 4 weight products, G, T_lig, ligB
  int* ib        = (int*)d_ws;
  int* lig_start = ib + 16;
  int* pro_start = ib + 56;
  bf16_t* wsb  = ((bf16_t*)d_ws) + 256;
  bf16_t* A1   = wsb;                         // Wq_lig^T Wk_pro
  bf16_t* B2   = A1   + DIM*DIM;              // Wk_lig^T Wq_pro
  bf16_t* PtTL = B2   + DIM*DIM;              // Wout_lig @ Wv_pro  (= M_lig^T)
  bf16_t* PtTP = PtTL + DIM*DIM;              // Wout_pro @ Wv_lig  (= M_pro^T)
  bf16_t* G    = PtTP + DIM*DIM;              // lig @ B2   [2048][256]  (pro-side K)
  bf16_t* T_lig= G    + (size_t)NLr*DIM;      // lig @ A1   [2048][256]  (lig-side Q)
  bf16_t* ligB = T_lig+ (size_t)NLr*DIM;      // bf16(lig)  [2048][256]  (pro-side V)

  float* outp = (float*)d_out;
  // proB: bf16(pro) [16384][256] in the d_out tail; read by lig attn, then
  // overwritten by pro-attn outputs (stream-ordered).
  bf16_t* proB = (bf16_t*)(outp + ((size_t)(NLr+NPr)*DIM - (size_t)NPr*DIM/2));

  hipLaunchKernelGGL(bounds_kernel, dim3(1), dim3(64), 0, stream,
                     lig_batch, pro_batch, lig_start, pro_start);

  dim3 gw(4,4), gl(NLr/64, 4);
  hipLaunchKernelGGL(wprod_atb, gw, dim3(256), 0, stream, Wq_lig, Wk_pro, A1);
  hipLaunchKernelGGL(wprod_atb, gw, dim3(256), 0, stream, Wk_lig, Wq_pro, B2);
  hipLaunchKernelGGL(wprod_ab,  gw, dim3(256), 0, stream, Wout_lig, Wv_pro, PtTL);
  hipLaunchKernelGGL(wprod_ab,  gw, dim3(256), 0, stream, Wout_pro, Wv_lig, PtTP);
  hipLaunchKernelGGL(gemm_ab, gl, dim3(256), 0, stream, lig, A1, T_lig);
  hipLaunchKernelGGL(gemm_ab, gl, dim3(256), 0, stream, lig, B2, G);
  hipLaunchKernelGGL(cast_bf16, dim3(NPr*DIM/1024), dim3(256), 0, stream, pro, proB, NPr*DIM);
  hipLaunchKernelGGL(cast_bf16, dim3(NLr*DIM/1024), dim3(256), 0, stream, lig, ligB, NLr*DIM);

  // ligand <- protein: Q=T_lig(bf16), K=V=proB; 2-way key-split, 128 blocks
  hipLaunchKernelGGL((attn2<0,2>), dim3(NLr/16), dim3(128), 0, stream,
                     (const void*)T_lig, proB, proB,
                     lig_pos, pro_pos, lig_batch, pro_start, PtTL,
                     lig, bout_lig, g_lig, b_lig, outp, 0, NPr);
  // protein <- ligand: Q=pro(fp32 hi/lo), K=G, V=ligB; 2 tiles/block, 512 blocks
  hipLaunchKernelGGL((attn2<1,1>), dim3(NPr/32), dim3(128), 0, stream,
                     (const void*)pro, G, ligB,
                     pro_pos, lig_pos, pro_batch, lig_start, PtTP,
                     pro, bout_pro, g_pro, b_pro, outp, NLr*DIM, NLr);
}

// Round 11
// 265.477 us; speedup vs baseline: 5.5237x; 1.2761x over previous
//
#include <hip/hip_runtime.h>

static constexpr int NLr = 2048;    // ligand rows
static constexpr int NPr = 16384;   // protein rows
static constexpr int DIM = 256;     // feature dim
static constexpr int NB  = 32;      // batch count

typedef unsigned short bf16_t;
using bf16x8 = __attribute__((ext_vector_type(8))) short;
using f32x4  = __attribute__((ext_vector_type(4))) float;

__device__ inline float bf2f(bf16_t u){
  union { unsigned int i; float f; } c; c.i = ((unsigned int)u) << 16; return c.f;
}
__device__ inline bf16_t f2bf(float f){
  union { float f; unsigned int i; } c; c.f = f;
  unsigned int x = c.i;
  return (bf16_t)((x + 0x7fffu + ((x >> 16) & 1u)) >> 16);  // RNE
}
__device__ inline float wave_sum(float x){
  #pragma unroll
  for (int off = 32; off; off >>= 1) x += __shfl_xor(x, off, 64);
  return x;
}
__device__ inline bf16x8 ldfrag_f32(const float* p){
  float4 a = *reinterpret_cast<const float4*>(p);
  float4 b = *reinterpret_cast<const float4*>(p + 4);
  bf16x8 r;
  r[0]=(short)f2bf(a.x); r[1]=(short)f2bf(a.y); r[2]=(short)f2bf(a.z); r[3]=(short)f2bf(a.w);
  r[4]=(short)f2bf(b.x); r[5]=(short)f2bf(b.y); r[6]=(short)f2bf(b.z); r[7]=(short)f2bf(b.w);
  return r;
}
// fp32 -> (hi, lo) bf16 pair
__device__ inline void hilo8(const float* p, bf16x8& hi, bf16x8& lo){
  #pragma unroll
  for (int i = 0; i < 8; i++){
    float v = p[i];
    bf16_t h = f2bf(v);
    hi[i] = (short)h;
    lo[i] = (short)f2bf(v - bf2f(h));
  }
}

// partial-buffer offsets inside d_out (floats). Stream-ordered reuse:
// attn_lig writes partials -> merge_lig consumes -> attn_pro overwrites region.
static constexpr int OPART_OFF  = 2621440;   // 512 * 4096 floats, ends at d_out end
static constexpr int MLPART_OFF = 2605056;   // 512 * 32 floats

// ---- batch block boundaries ----
__global__ void bounds_kernel(const int* __restrict__ lb, const int* __restrict__ pb,
                              int* __restrict__ ls, int* __restrict__ ps){
  int t = threadIdx.x;
  if (t <= NB){
    int lo = 0, hi = NLr;
    while (lo < hi){ int mid = (lo + hi) >> 1; if (lb[mid] < t) lo = mid + 1; else hi = mid; }
    ls[t] = lo;
    lo = 0; hi = NPr;
    while (lo < hi){ int mid = (lo + hi) >> 1; if (pb[mid] < t) lo = mid + 1; else hi = mid; }
    ps[t] = lo;
  }
}

// ---- 4 weight products in one launch: z<2 -> A^T B ; z>=2 -> A B ----
__global__ __launch_bounds__(256) void wprod4(
    const float* __restrict__ Wq_lig, const float* __restrict__ Wk_pro,
    const float* __restrict__ Wk_lig, const float* __restrict__ Wq_pro,
    const float* __restrict__ Wout_lig, const float* __restrict__ Wv_pro,
    const float* __restrict__ Wout_pro, const float* __restrict__ Wv_lig,
    bf16_t* __restrict__ A1, bf16_t* __restrict__ B2,
    bf16_t* __restrict__ PtTL, bf16_t* __restrict__ PtTP){
  __shared__ float Sa[1088];
  __shared__ float Sb[1088];
  const int z = blockIdx.z;
  const float *A, *B; bf16_t* C;
  if      (z == 0){ A = Wq_lig;   B = Wk_pro; C = A1;   }
  else if (z == 1){ A = Wk_lig;   B = Wq_pro; C = B2;   }
  else if (z == 2){ A = Wout_lig; B = Wv_pro; C = PtTL; }
  else            { A = Wout_pro; B = Wv_lig; C = PtTP; }
  const int t  = threadIdx.x;
  const int tx = t & 15, ty = t >> 4;
  const int bm = blockIdx.x, bn = blockIdx.y;
  float acc[4][4] = {};
  if (z < 2){
    // C[i,n] = sum_k A[k,i]*B[k,n]
    float (*As)[68] = (float(*)[68])Sa;
    float (*Bs)[68] = (float(*)[68])Sb;
    const int kk = t >> 4, c0 = (t & 15) << 2;
    for (int kt = 0; kt < DIM; kt += 16){
      float4 av = *reinterpret_cast<const float4*>(A + (size_t)(kt+kk)*DIM + bm*64 + c0);
      float4 bv = *reinterpret_cast<const float4*>(B + (size_t)(kt+kk)*DIM + bn*64 + c0);
      As[kk][c0+0]=av.x; As[kk][c0+1]=av.y; As[kk][c0+2]=av.z; As[kk][c0+3]=av.w;
      Bs[kk][c0+0]=bv.x; Bs[kk][c0+1]=bv.y; Bs[kk][c0+2]=bv.z; Bs[kk][c0+3]=bv.w;
      __syncthreads();
      #pragma unroll
      for (int k = 0; k < 16; k++){
        float a[4], b[4];
        #pragma unroll
        for (int i = 0; i < 4; i++) a[i] = As[k][ty*4+i];
        #pragma unroll
        for (int j = 0; j < 4; j++) b[j] = Bs[k][tx*4+j];
        #pragma unroll
        for (int i = 0; i < 4; i++)
          #pragma unroll
          for (int j = 0; j < 4; j++) acc[i][j] += a[i]*b[j];
      }
      __syncthreads();
    }
  } else {
    // C[i,n] = sum_k A[i,k]*B[k,n]
    float (*As)[17] = (float(*)[17])Sa;
    float (*Bs)[68] = (float(*)[68])Sb;
    const int r  = t >> 2, k0 = (t & 3) << 2;
    const int kk = t >> 4, c0 = (t & 15) << 2;
    for (int kt = 0; kt < DIM; kt += 16){
      float4 av = *reinterpret_cast<const float4*>(A + (size_t)(bm*64+r)*DIM + kt + k0);
      float4 bv = *reinterpret_cast<const float4*>(B + (size_t)(kt+kk)*DIM + bn*64 + c0);
      As[r][k0+0]=av.x; As[r][k0+1]=av.y; As[r][k0+2]=av.z; As[r][k0+3]=av.w;
      Bs[kk][c0+0]=bv.x; Bs[kk][c0+1]=bv.y; Bs[kk][c0+2]=bv.z; Bs[kk][c0+3]=bv.w;
      __syncthreads();
      #pragma unroll
      for (int k = 0; k < 16; k++){
        float a[4], b[4];
        #pragma unroll
        for (int i = 0; i < 4; i++) a[i] = As[ty*4+i][k];
        #pragma unroll
        for (int j = 0; j < 4; j++) b[j] = Bs[k][tx*4+j];
        #pragma unroll
        for (int i = 0; i < 4; i++)
          #pragma unroll
          for (int j = 0; j < 4; j++) acc[i][j] += a[i]*b[j];
      }
      __syncthreads();
    }
  }
  #pragma unroll
  for (int i = 0; i < 4; i++){
    ushort4 o;
    o.x=f2bf(acc[i][0]); o.y=f2bf(acc[i][1]); o.z=f2bf(acc[i][2]); o.w=f2bf(acc[i][3]);
    *reinterpret_cast<ushort4*>(C + (size_t)(bm*64+ty*4+i)*DIM + bn*64 + tx*4) = o;
  }
}

// ---- two ligand projections in one launch: z selects B/C ----
__global__ __launch_bounds__(256) void gemm2(
    const float* __restrict__ A, const bf16_t* __restrict__ Ba, const bf16_t* __restrict__ Bb,
    bf16_t* __restrict__ Ca, bf16_t* __restrict__ Cb){
  const bf16_t* B = blockIdx.z ? Bb : Ba;
  bf16_t*       C = blockIdx.z ? Cb : Ca;
  __shared__ float As[64][17];
  __shared__ float Bs[16][68];
  const int t  = threadIdx.x;
  const int r  = t >> 2, k0 = (t & 3) << 2;
  const int kk = t >> 4, c0 = (t & 15) << 2;
  const int tx = t & 15, ty = t >> 4;
  const int bm = blockIdx.x, bn = blockIdx.y;
  float acc[4][4] = {};
  for (int kt = 0; kt < DIM; kt += 16){
    float4 av = *reinterpret_cast<const float4*>(A + (size_t)(bm*64+r)*DIM + kt + k0);
    ushort4 bu = *reinterpret_cast<const ushort4*>(B + (size_t)(kt+kk)*DIM + bn*64 + c0);
    As[r][k0+0]=av.x; As[r][k0+1]=av.y; As[r][k0+2]=av.z; As[r][k0+3]=av.w;
    Bs[kk][c0+0]=bf2f(bu.x); Bs[kk][c0+1]=bf2f(bu.y);
    Bs[kk][c0+2]=bf2f(bu.z); Bs[kk][c0+3]=bf2f(bu.w);
    __syncthreads();
    #pragma unroll
    for (int k = 0; k < 16; k++){
      float a[4], b[4];
      #pragma unroll
      for (int i = 0; i < 4; i++) a[i] = As[ty*4+i][k];
      #pragma unroll
      for (int j = 0; j < 4; j++) b[j] = Bs[k][tx*4+j];
      #pragma unroll
      for (int i = 0; i < 4; i++)
        #pragma unroll
        for (int j = 0; j < 4; j++) acc[i][j] += a[i]*b[j];
    }
    __syncthreads();
  }
  #pragma unroll
  for (int i = 0; i < 4; i++){
    ushort4 o;
    o.x=f2bf(acc[i][0]); o.y=f2bf(acc[i][1]); o.z=f2bf(acc[i][2]); o.w=f2bf(acc[i][3]);
    *reinterpret_cast<ushort4*>(C + (size_t)(bm*64+ty*4+i)*DIM + bn*64 + tx*4) = o;
  }
}

// ==== ligand attention: 128 tiles x 4 key-splits, partials to d_out tail ====
__global__ __launch_bounds__(128) void attn_lig(
    const bf16_t* __restrict__ Qb, const float* __restrict__ Kf,
    const float* __restrict__ posA, const float* __restrict__ posB,
    const int* __restrict__ batchA, const int* __restrict__ startB,
    float* __restrict__ dout, int NK){
  __shared__ __align__(16) char raw[36864];   // Vlds [256][72] bf16; later Ob [2][16][256] f32
  __shared__ bf16_t Pbuf[2][16][40];
  __shared__ float  mlb[2][2][16];
  bf16_t* Vlds = (bf16_t*)raw;
  float*  Ob   = (float*)raw;
  float* Opart  = dout + OPART_OFF;
  float* mlpart = dout + MLPART_OFF;

  const int t = threadIdx.x, wl = t >> 6, lane = t & 63;
  const int qrow = lane & 15, q4 = lane >> 4;
  const int tile = blockIdx.x >> 2, split = blockIdx.x & 3;
  const int row0 = tile * 16, pidx = blockIdx.x;

  const int rb = batchA[row0 + qrow];
  const int j0 = startB[rb], j1 = startB[rb + 1];
  const float ax = posA[(size_t)(row0+qrow)*3+0];
  const float ay = posA[(size_t)(row0+qrow)*3+1];
  const float az = posA[(size_t)(row0+qrow)*3+2];
  const int kmin = startB[batchA[row0]];
  const int kmax = startB[batchA[row0 + 15] + 1];
  const int base = kmin & ~63;

  bf16x8 qf[8];
  #pragma unroll
  for (int s = 0; s < 8; s++)
    qf[s] = *reinterpret_cast<const bf16x8*>(Qb + (size_t)(row0+qrow)*DIM + s*32 + q4*8);

  f32x4 O[16];
  #pragma unroll
  for (int i = 0; i < 16; i++) O[i] = (f32x4){0.f,0.f,0.f,0.f};
  float m_ = -3.0e38f, l_ = 0.f;

  for (int c = base + split*64; c < kmax; c += 256){
    __syncthreads();
    {  // stage 64 keys x 256 dims, fp32 -> bf16 transposed, batched loads
      const int key = t & 63, half = t >> 6;
      const float* src = Kf + (size_t)min(c + key, NK-1)*DIM + half*128;
      #pragma unroll
      for (int gch = 0; gch < 4; gch++){
        float4 tmp[8];
        #pragma unroll
        for (int u = 0; u < 8; u++)
          tmp[u] = *reinterpret_cast<const float4*>(src + gch*32 + u*4);
        #pragma unroll
        for (int u = 0; u < 8; u++){
          int d = half*128 + gch*32 + u*4;
          Vlds[(d+0)*72 + key] = f2bf(tmp[u].x);
          Vlds[(d+1)*72 + key] = f2bf(tmp[u].y);
          Vlds[(d+2)*72 + key] = f2bf(tmp[u].z);
          Vlds[(d+3)*72 + key] = f2bf(tmp[u].w);
        }
      }
    }
    __syncthreads();

    const int kc0 = c + wl*32, colbase = wl*32;
    f32x4 a0 = (f32x4){0.f,0.f,0.f,0.f}, a1 = a0;
    const float* kr0 = Kf + (size_t)min(kc0 + qrow,      NK-1)*DIM;
    const float* kr1 = Kf + (size_t)min(kc0 + 16 + qrow, NK-1)*DIM;
    #pragma unroll
    for (int s = 0; s < 8; s++){
      bf16x8 ka = ldfrag_f32(kr0 + s*32 + q4*8);
      bf16x8 kb = ldfrag_f32(kr1 + s*32 + q4*8);
      a0 = __builtin_amdgcn_mfma_f32_16x16x32_bf16(ka, qf[s], a0, 0, 0, 0);
      a1 = __builtin_amdgcn_mfma_f32_16x16x32_bf16(kb, qf[s], a1, 0, 0, 0);
    }
    float sc[2][4]; bool vm[2][4];
    float cm = -3.0e38f;
    #pragma unroll
    for (int h = 0; h < 2; h++)
      #pragma unroll
      for (int r = 0; r < 4; r++){
        int key = kc0 + h*16 + q4*4 + r;
        bool vld = (key >= j0) && (key < j1);
        int kc = min(key, NK-1);
        float bx = posB[(size_t)kc*3+0], by = posB[(size_t)kc*3+1], bz = posB[(size_t)kc*3+2];
        float dx = ax-bx, dy = ay-by, dz = az-bz;
        float dist = sqrtf(fmaxf(dx*dx + dy*dy + dz*dz, 1e-12f));
        float sv = (h ? a1[r] : a0[r]) * 0.0625f + __expf(-0.1f*dist);
        sc[h][r] = vld ? sv : -3.0e38f;
        vm[h][r] = vld;
        cm = fmaxf(cm, sc[h][r]);
      }
    cm = fmaxf(cm, __shfl_xor(cm, 16));
    cm = fmaxf(cm, __shfl_xor(cm, 32));
    float mn = fmaxf(m_, cm);
    float aa = __expf(m_ - mn);
    float p[2][4]; float ps = 0.f;
    #pragma unroll
    for (int h = 0; h < 2; h++)
      #pragma unroll
      for (int r = 0; r < 4; r++){
        p[h][r] = vm[h][r] ? __expf(sc[h][r] - mn) : 0.f;
        ps += p[h][r];
      }
    ps += __shfl_xor(ps, 16);
    ps += __shfl_xor(ps, 32);
    l_ = l_*aa + ps;
    m_ = mn;
    ushort4 w0, w1;
    w0.x=f2bf(p[0][0]); w0.y=f2bf(p[0][1]); w0.z=f2bf(p[0][2]); w0.w=f2bf(p[0][3]);
    w1.x=f2bf(p[1][0]); w1.y=f2bf(p[1][1]); w1.z=f2bf(p[1][2]); w1.w=f2bf(p[1][3]);
    *reinterpret_cast<ushort4*>(&Pbuf[wl][qrow][q4*4])      = w0;
    *reinterpret_cast<ushort4*>(&Pbuf[wl][qrow][16 + q4*4]) = w1;
    float af0 = __shfl(aa, q4*4+0), af1 = __shfl(aa, q4*4+1);
    float af2 = __shfl(aa, q4*4+2), af3 = __shfl(aa, q4*4+3);
    #pragma unroll
    for (int i = 0; i < 16; i++){
      O[i][0]*=af0; O[i][1]*=af1; O[i][2]*=af2; O[i][3]*=af3;
    }
    bf16x8 pa = *reinterpret_cast<const bf16x8*>(&Pbuf[wl][qrow][q4*8]);
    #pragma unroll
    for (int i = 0; i < 16; i++){
      const bf16_t* vp = Vlds + (size_t)(i*16 + qrow)*72 + colbase + q4*8;
      bf16x8 vb = *reinterpret_cast<const bf16x8*>(vp);
      O[i] = __builtin_amdgcn_mfma_f32_16x16x32_bf16(pa, vb, O[i], 0, 0, 0);
    }
  }

  // in-block 2-wave merge (un-normalized) -> write partial
  __syncthreads();
  if (lane < 16){ mlb[wl][0][lane] = m_; mlb[wl][1][lane] = l_; }
  #pragma unroll
  for (int i = 0; i < 16; i++)
    #pragma unroll
    for (int r = 0; r < 4; r++)
      Ob[wl*4096 + (q4*4+r)*256 + i*16 + qrow] = O[i][r];
  __syncthreads();
  for (int e = t; e < 4096; e += 128){
    int row = e >> 8, d = e & 255;
    float m0 = mlb[0][0][row], m1 = mlb[1][0][row];
    float mg = fmaxf(m0, m1);
    float f0 = __expf(m0 - mg), f1 = __expf(m1 - mg);
    Opart[(size_t)pidx*4096 + row*256 + d] = Ob[row*256 + d]*f0 + Ob[4096 + row*256 + d]*f1;
  }
  if (t < 16){
    float m0 = mlb[0][0][t], l0 = mlb[0][1][t];
    float m1 = mlb[1][0][t], l1 = mlb[1][1][t];
    float mg = fmaxf(m0, m1);
    mlpart[pidx*32 + t]      = mg;
    mlpart[pidx*32 + 16 + t] = l0*__expf(m0-mg) + l1*__expf(m1-mg);
  }
}

// ==== ligand merge + out-projection + residual + LN ====
__global__ __launch_bounds__(128) void merge_lig(
    const float* __restrict__ dpart, const bf16_t* __restrict__ PtT,
    const float* __restrict__ X, const float* __restrict__ bo,
    const float* __restrict__ g, const float* __restrict__ bb,
    float* __restrict__ out){
  __shared__ float ctxl[16*260];
  __shared__ float Yb[16*260];
  __shared__ float wgt[4][16];
  __shared__ float dens[16];
  const float* Opart  = dpart + OPART_OFF;
  const float* mlpart = dpart + MLPART_OFF;
  const int t = threadIdx.x, wl = t >> 6, lane = t & 63;
  const int qrow = lane & 15, q4 = lane >> 4;
  const int tile = blockIdx.x, row0 = tile*16;
  if (t < 16){
    float mm[4], ll[4], mg = -3.0e38f;
    #pragma unroll
    for (int s = 0; s < 4; s++){
      mm[s] = mlpart[(tile*4+s)*32 + t];
      ll[s] = mlpart[(tile*4+s)*32 + 16 + t];
      mg = fmaxf(mg, mm[s]);
    }
    float den = 0.f;
    #pragma unroll
    for (int s = 0; s < 4; s++){
      float w = __expf(mm[s] - mg);
      wgt[s][t] = w;
      den += ll[s]*w;
    }
    dens[t] = den;
  }
  __syncthreads();
  for (int e = t; e < 4096; e += 128){
    int row = e >> 8, d = e & 255;
    float acc = 0.f;
    #pragma unroll
    for (int s = 0; s < 4; s++)
      acc += Opart[((size_t)(tile*4+s))*4096 + row*256 + d] * wgt[s][row];
    float dd = dens[row];
    ctxl[row*260 + d] = (dd > 0.f) ? acc/dd : 0.f;
  }
  __syncthreads();
  // Y = ctx_hi*M + ctx_lo*M
  f32x4 Y[8];
  #pragma unroll
  for (int i = 0; i < 8; i++) Y[i] = (f32x4){0.f,0.f,0.f,0.f};
  #pragma unroll
  for (int s = 0; s < 8; s++){
    bf16x8 ca, cl;
    hilo8(ctxl + qrow*260 + s*32 + q4*8, ca, cl);
    #pragma unroll
    for (int tt = 0; tt < 8; tt++){
      const bf16_t* pb = PtT + (size_t)((wl*8+tt)*16 + qrow)*DIM + s*32 + q4*8;
      bf16x8 mb = *reinterpret_cast<const bf16x8*>(pb);
      Y[tt] = __builtin_amdgcn_mfma_f32_16x16x32_bf16(ca, mb, Y[tt], 0, 0, 0);
      Y[tt] = __builtin_amdgcn_mfma_f32_16x16x32_bf16(cl, mb, Y[tt], 0, 0, 0);
    }
  }
  #pragma unroll
  for (int tt = 0; tt < 8; tt++)
    #pragma unroll
    for (int r = 0; r < 4; r++)
      Yb[(q4*4+r)*260 + (wl*8+tt)*16 + qrow] = Y[tt][r];
  __syncthreads();
  for (int i = 0; i < 8; i++){
    int r = wl*8 + i, grow = row0 + r;
    float4 yv = *reinterpret_cast<const float4*>(&Yb[r*260 + 4*lane]);
    float4 xv = *reinterpret_cast<const float4*>(X  + (size_t)grow*DIM + 4*lane);
    float4 bv = *reinterpret_cast<const float4*>(bo + 4*lane);
    float4 gv = *reinterpret_cast<const float4*>(g  + 4*lane);
    float4 b2 = *reinterpret_cast<const float4*>(bb + 4*lane);
    float v0 = xv.x + yv.x + bv.x, v1 = xv.y + yv.y + bv.y;
    float v2 = xv.z + yv.z + bv.z, v3 = xv.w + yv.w + bv.w;
    float sum = wave_sum(v0+v1+v2+v3);
    float ssq = wave_sum(v0*v0+v1*v1+v2*v2+v3*v3);
    float mu  = sum * (1.0f/DIM);
    float var = ssq * (1.0f/DIM) - mu*mu;
    float rr  = rsqrtf(fmaxf(var, 0.f) + 1e-5f);
    float4 o;
    o.x = (v0-mu)*rr*gv.x + b2.x;
    o.y = (v1-mu)*rr*gv.y + b2.y;
    o.z = (v2-mu)*rr*gv.z + b2.z;
    o.w = (v3-mu)*rr*gv.w + b2.w;
    *reinterpret_cast<float4*>(out + (size_t)grow*DIM + 4*lane) = o;
  }
}

// ==== protein attention: 2 tiles/block (one per wave), shared 32-key staging ====
__global__ __launch_bounds__(128) void attn_pro(
    const float* __restrict__ Qf, const bf16_t* __restrict__ Kb,
    const float* __restrict__ Vf,
    const float* __restrict__ posA, const float* __restrict__ posB,
    const int* __restrict__ batchA, const int* __restrict__ startB,
    const bf16_t* __restrict__ PtT,
    const float* __restrict__ X, const float* __restrict__ bo,
    const float* __restrict__ g, const float* __restrict__ bb,
    float* __restrict__ out, int out_off, int NK){
  __shared__ __align__(16) char raw[33280];  // Vlds [256][40] bf16; later ctxl [2][16][260] f32
  __shared__ bf16_t Pbuf[2][16][40];
  bf16_t* Vlds = (bf16_t*)raw;
  float*  ctxl = (float*)raw;

  const int t = threadIdx.x, wl = t >> 6, lane = t & 63;
  const int qrow = lane & 15, q4 = lane >> 4;
  const int row0b = blockIdx.x * 32, row0 = row0b + wl*16;

  const int rb = batchA[row0 + qrow];
  const int j0 = startB[rb], j1 = startB[rb + 1];
  const float ax = posA[(size_t)(row0+qrow)*3+0];
  const float ay = posA[(size_t)(row0+qrow)*3+1];
  const float az = posA[(size_t)(row0+qrow)*3+2];
  const int kmin = startB[batchA[row0b]];
  const int kmax = startB[batchA[row0b + 31] + 1];
  const int base = kmin & ~31;

  bf16x8 qf[8], ql[8];
  #pragma unroll
  for (int s = 0; s < 8; s++)
    hilo8(Qf + (size_t)(row0+qrow)*DIM + s*32 + q4*8, qf[s], ql[s]);

  f32x4 O[16];
  #pragma unroll
  for (int i = 0; i < 16; i++) O[i] = (f32x4){0.f,0.f,0.f,0.f};
  float m_ = -3.0e38f, l_ = 0.f;

  for (int c = base; c < kmax; c += 32){
    __syncthreads();
    {  // stage 32 keys x 256 dims from fp32, batched
      const int key = t & 31, qtr = t >> 5;
      const float* src = Vf + (size_t)min(c + key, NK-1)*DIM + qtr*64;
      #pragma unroll
      for (int gch = 0; gch < 2; gch++){
        float4 tmp[8];
        #pragma unroll
        for (int u = 0; u < 8; u++)
          tmp[u] = *reinterpret_cast<const float4*>(src + gch*32 + u*4);
        #pragma unroll
        for (int u = 0; u < 8; u++){
          int d = qtr*64 + gch*32 + u*4;
          Vlds[(d+0)*40 + key] = f2bf(tmp[u].x);
          Vlds[(d+1)*40 + key] = f2bf(tmp[u].y);
          Vlds[(d+2)*40 + key] = f2bf(tmp[u].z);
          Vlds[(d+3)*40 + key] = f2bf(tmp[u].w);
        }
      }
    }
    __syncthreads();

    f32x4 a0 = (f32x4){0.f,0.f,0.f,0.f}, a1 = a0;
    const bf16_t* kr0 = Kb + (size_t)min(c + qrow,      NK-1)*DIM;
    const bf16_t* kr1 = Kb + (size_t)min(c + 16 + qrow, NK-1)*DIM;
    #pragma unroll
    for (int s = 0; s < 8; s++){
      bf16x8 ka = *reinterpret_cast<const bf16x8*>(kr0 + s*32 + q4*8);
      bf16x8 kb = *reinterpret_cast<const bf16x8*>(kr1 + s*32 + q4*8);
      a0 = __builtin_amdgcn_mfma_f32_16x16x32_bf16(ka, qf[s], a0, 0, 0, 0);
      a1 = __builtin_amdgcn_mfma_f32_16x16x32_bf16(kb, qf[s], a1, 0, 0, 0);
      a0 = __builtin_amdgcn_mfma_f32_16x16x32_bf16(ka, ql[s], a0, 0, 0, 0);
      a1 = __builtin_amdgcn_mfma_f32_16x16x32_bf16(kb, ql[s], a1, 0, 0, 0);
    }
    float sc[2][4]; bool vm[2][4];
    float cm = -3.0e38f;
    #pragma unroll
    for (int h = 0; h < 2; h++)
      #pragma unroll
      for (int r = 0; r < 4; r++){
        int key = c + h*16 + q4*4 + r;
        bool vld = (key >= j0) && (key < j1);
        int kc = min(key, NK-1);
        float bx = posB[(size_t)kc*3+0], by = posB[(size_t)kc*3+1], bz = posB[(size_t)kc*3+2];
        float dx = ax-bx, dy = ay-by, dz = az-bz;
        float dist = sqrtf(fmaxf(dx*dx + dy*dy + dz*dz, 1e-12f));
        float sv = (h ? a1[r] : a0[r]) * 0.0625f + __expf(-0.1f*dist);
        sc[h][r] = vld ? sv : -3.0e38f;
        vm[h][r] = vld;
        cm = fmaxf(cm, sc[h][r]);
      }
    cm = fmaxf(cm, __shfl_xor(cm, 16));
    cm = fmaxf(cm, __shfl_xor(cm, 32));
    float mn = fmaxf(m_, cm);
    float aa = __expf(m_ - mn);
    float p[2][4]; float ps = 0.f;
    #pragma unroll
    for (int h = 0; h < 2; h++)
      #pragma unroll
      for (int r = 0; r < 4; r++){
        p[h][r] = vm[h][r] ? __expf(sc[h][r] - mn) : 0.f;
        ps += p[h][r];
      }
    ps += __shfl_xor(ps, 16);
    ps += __shfl_xor(ps, 32);
    l_ = l_*aa + ps;
    m_ = mn;
    ushort4 w0, w1;
    w0.x=f2bf(p[0][0]); w0.y=f2bf(p[0][1]); w0.z=f2bf(p[0][2]); w0.w=f2bf(p[0][3]);
    w1.x=f2bf(p[1][0]); w1.y=f2bf(p[1][1]); w1.z=f2bf(p[1][2]); w1.w=f2bf(p[1][3]);
    *reinterpret_cast<ushort4*>(&Pbuf[wl][qrow][q4*4])      = w0;
    *reinterpret_cast<ushort4*>(&Pbuf[wl][qrow][16 + q4*4]) = w1;
    float af0 = __shfl(aa, q4*4+0), af1 = __shfl(aa, q4*4+1);
    float af2 = __shfl(aa, q4*4+2), af3 = __shfl(aa, q4*4+3);
    #pragma unroll
    for (int i = 0; i < 16; i++){
      O[i][0]*=af0; O[i][1]*=af1; O[i][2]*=af2; O[i][3]*=af3;
    }
    bf16x8 pa = *reinterpret_cast<const bf16x8*>(&Pbuf[wl][qrow][q4*8]);
    #pragma unroll
    for (int i = 0; i < 16; i++){
      const bf16_t* vp = Vlds + (size_t)(i*16 + qrow)*40 + q4*8;
      bf16x8 vb = *reinterpret_cast<const bf16x8*>(vp);
      O[i] = __builtin_amdgcn_mfma_f32_16x16x32_bf16(pa, vb, O[i], 0, 0, 0);
    }
  }

  __syncthreads();   // Vlds readers done; raw becomes ctxl
  {
    float lr0 = __shfl(l_, q4*4+0), lr1 = __shfl(l_, q4*4+1);
    float lr2 = __shfl(l_, q4*4+2), lr3 = __shfl(l_, q4*4+3);
    float i0 = lr0>0.f?1.f/lr0:0.f, i1 = lr1>0.f?1.f/lr1:0.f;
    float i2 = lr2>0.f?1.f/lr2:0.f, i3 = lr3>0.f?1.f/lr3:0.f;
    float* cw = ctxl + wl*4160;
    #pragma unroll
    for (int i = 0; i < 16; i++){
      cw[(q4*4+0)*260 + i*16+qrow] = O[i][0]*i0;
      cw[(q4*4+1)*260 + i*16+qrow] = O[i][1]*i1;
      cw[(q4*4+2)*260 + i*16+qrow] = O[i][2]*i2;
      cw[(q4*4+3)*260 + i*16+qrow] = O[i][3]*i3;
    }
  }
  const float* cw = ctxl + wl*4160;
  f32x4 Y[16];
  #pragma unroll
  for (int i = 0; i < 16; i++) Y[i] = (f32x4){0.f,0.f,0.f,0.f};
  #pragma unroll
  for (int s = 0; s < 8; s++){
    bf16x8 ca, cl;
    hilo8(cw + qrow*260 + s*32 + q4*8, ca, cl);
    #pragma unroll
    for (int tt = 0; tt < 16; tt++){
      const bf16_t* pb = PtT + (size_t)(tt*16 + qrow)*DIM + s*32 + q4*8;
      bf16x8 mb = *reinterpret_cast<const bf16x8*>(pb);
      Y[tt] = __builtin_amdgcn_mfma_f32_16x16x32_bf16(ca, mb, Y[tt], 0, 0, 0);
      Y[tt] = __builtin_amdgcn_mfma_f32_16x16x32_bf16(cl, mb, Y[tt], 0, 0, 0);
    }
  }
  float* YB = ctxl + wl*4160;
  #pragma unroll
  for (int tt = 0; tt < 16; tt++)
    #pragma unroll
    for (int r = 0; r < 4; r++)
      YB[(q4*4+r)*260 + tt*16 + qrow] = Y[tt][r];

  for (int i = 0; i < 16; i++){
    int grow = row0 + i;
    float4 yv = *reinterpret_cast<const float4*>(&YB[i*260 + 4*lane]);
    float4 xv = *reinterpret_cast<const float4*>(X  + (size_t)grow*DIM + 4*lane);
    float4 bv = *reinterpret_cast<const float4*>(bo + 4*lane);
    float4 gv = *reinterpret_cast<const float4*>(g  + 4*lane);
    float4 b2 = *reinterpret_cast<const float4*>(bb + 4*lane);
    float v0 = xv.x + yv.x + bv.x, v1 = xv.y + yv.y + bv.y;
    float v2 = xv.z + yv.z + bv.z, v3 = xv.w + yv.w + bv.w;
    float sum = wave_sum(v0+v1+v2+v3);
    float ssq = wave_sum(v0*v0+v1*v1+v2*v2+v3*v3);
    float mu  = sum * (1.0f/DIM);
    float var = ssq * (1.0f/DIM) - mu*mu;
    float rr  = rsqrtf(fmaxf(var, 0.f) + 1e-5f);
    float4 o;
    o.x = (v0-mu)*rr*gv.x + b2.x;
    o.y = (v1-mu)*rr*gv.y + b2.y;
    o.z = (v2-mu)*rr*gv.z + b2.z;
    o.w = (v3-mu)*rr*gv.w + b2.w;
    *reinterpret_cast<float4*>(out + (size_t)out_off + (size_t)grow*DIM + 4*lane) = o;
  }
}

extern "C" void kernel_launch(void* const* d_in, const int* in_sizes, int n_in,
                              void* d_out, int out_size, void* d_ws, size_t ws_size,
                              hipStream_t stream){
  const float* lig      = (const float*)d_in[0];
  const float* pro      = (const float*)d_in[1];
  const float* lig_pos  = (const float*)d_in[2];
  const float* pro_pos  = (const float*)d_in[3];
  const int*   lig_batch= (const int*)d_in[4];
  const int*   pro_batch= (const int*)d_in[5];
  const float* Wq_lig   = (const float*)d_in[6];
  const float* Wk_pro   = (const float*)d_in[7];
  const float* Wv_pro   = (const float*)d_in[8];
  const float* Wq_pro   = (const float*)d_in[9];
  const float* Wk_lig   = (const float*)d_in[10];
  const float* Wv_lig   = (const float*)d_in[11];
  const float* Wout_lig = (const float*)d_in[12];
  const float* bout_lig = (const float*)d_in[13];
  const float* Wout_pro = (const float*)d_in[14];
  const float* bout_pro = (const float*)d_in[15];
  const float* g_lig    = (const float*)d_in[16];
  const float* b_lig    = (const float*)d_in[17];
  const float* g_pro    = (const float*)d_in[18];
  const float* b_pro    = (const float*)d_in[19];

  // ws (~2.6 MB, proven size): ints, 4 weight products, G, T_lig
  int* ib        = (int*)d_ws;
  int* lig_start = ib + 16;
  int* pro_start = ib + 56;
  bf16_t* wsb  = ((bf16_t*)d_ws) + 256;
  bf16_t* A1   = wsb;                         // Wq_lig^T Wk_pro
  bf16_t* B2   = A1   + DIM*DIM;              // Wk_lig^T Wq_pro
  bf16_t* PtTL = B2   + DIM*DIM;              // Wout_lig @ Wv_pro  (= M_lig^T)
  bf16_t* PtTP = PtTL + DIM*DIM;              // Wout_pro @ Wv_lig  (= M_pro^T)
  bf16_t* G    = PtTP + DIM*DIM;              // lig @ B2   [2048][256]  (pro-side K)
  bf16_t* T_lig= G    + (size_t)NLr*DIM;      // lig @ A1   [2048][256]  (lig-side Q)

  float* outp = (float*)d_out;

  hipLaunchKernelGGL(bounds_kernel, dim3(1), dim3(64), 0, stream,
                     lig_batch, pro_batch, lig_start, pro_start);
  hipLaunchKernelGGL(wprod4, dim3(4,4,4), dim3(256), 0, stream,
                     Wq_lig, Wk_pro, Wk_lig, Wq_pro, Wout_lig, Wv_pro, Wout_pro, Wv_lig,
                     A1, B2, PtTL, PtTP);
  hipLaunchKernelGGL(gemm2, dim3(NLr/64, 4, 2), dim3(256), 0, stream,
                     lig, A1, B2, T_lig, G);

  // ligand <- protein: partials into d_out tail, then merge
  hipLaunchKernelGGL(attn_lig, dim3(NLr/16*4), dim3(128), 0, stream,
                     T_lig, pro, lig_pos, pro_pos, lig_batch, pro_start, outp, NPr);
  hipLaunchKernelGGL(merge_lig, dim3(NLr/16), dim3(128), 0, stream,
                     outp, PtTL, lig, bout_lig, g_lig, b_lig, outp);

  // protein <- ligand (overwrites partial region only after merge consumed it)
  hipLaunchKernelGGL(attn_pro, dim3(NPr/32), dim3(128), 0, stream,
                     pro, G, lig, pro_pos, lig_pos, pro_batch, lig_start, PtTP,
                     pro, bout_pro, g_pro, b_pro, outp, NLr*DIM, NLr);
}